// Round 3
// baseline (1633.904 us; speedup 1.0000x reference)
//
#include <hip/hip_runtime.h>

#define BB 32
#define SS 512
#define EE 512
#define NHH 2
#define HDD 256
#define E3 1536
#define NT 24
#define MR (BB*SS)   // 16384

#define WAVE_BAR() __builtin_amdgcn_wave_barrier()

// =====================================================================
// GEMM: C[M][N] = A[M][K] . B[N][K]^T + bias[N], optional ReLU.
// 128x128 block tile, 256 threads, 8x8 per thread, BK=16.
// =====================================================================
__global__ __launch_bounds__(256) void gemm_bt128(
    const float* __restrict__ A, const float* __restrict__ Bm,
    const float* __restrict__ bias, float* __restrict__ C,
    int M, int N, int K, int relu)
{
    __shared__ __align__(16) float As[16][128];
    __shared__ __align__(16) float Bs[16][128];
    const int t  = threadIdx.x;
    const int mt = blockIdx.y * 128;
    const int nt = blockIdx.x * 128;
    const int tr = t >> 4;          // 0..15
    const int tc = t & 15;          // 0..15
    const int lr = t >> 2;          // 0..63
    const int lk = (t & 3) * 4;     // 0,4,8,12

    float acc[8][8];
#pragma unroll
    for (int i = 0; i < 8; ++i)
#pragma unroll
        for (int j = 0; j < 8; ++j) acc[i][j] = 0.f;

    for (int k0 = 0; k0 < K; k0 += 16) {
        float4 a0 = *(const float4*)(A  + (size_t)(mt + lr)      * K + k0 + lk);
        float4 a1 = *(const float4*)(A  + (size_t)(mt + lr + 64) * K + k0 + lk);
        float4 b0 = *(const float4*)(Bm + (size_t)(nt + lr)      * K + k0 + lk);
        float4 b1 = *(const float4*)(Bm + (size_t)(nt + lr + 64) * K + k0 + lk);
        __syncthreads();
        As[lk+0][lr]    = a0.x; As[lk+1][lr]    = a0.y; As[lk+2][lr]    = a0.z; As[lk+3][lr]    = a0.w;
        As[lk+0][lr+64] = a1.x; As[lk+1][lr+64] = a1.y; As[lk+2][lr+64] = a1.z; As[lk+3][lr+64] = a1.w;
        Bs[lk+0][lr]    = b0.x; Bs[lk+1][lr]    = b0.y; Bs[lk+2][lr]    = b0.z; Bs[lk+3][lr]    = b0.w;
        Bs[lk+0][lr+64] = b1.x; Bs[lk+1][lr+64] = b1.y; Bs[lk+2][lr+64] = b1.z; Bs[lk+3][lr+64] = b1.w;
        __syncthreads();
#pragma unroll
        for (int kk = 0; kk < 16; ++kk) {
            float4 aA = *(const float4*)&As[kk][tr*8];
            float4 aB = *(const float4*)&As[kk][tr*8+4];
            float4 bA = *(const float4*)&Bs[kk][tc*8];
            float4 bB = *(const float4*)&Bs[kk][tc*8+4];
            float av[8] = {aA.x,aA.y,aA.z,aA.w,aB.x,aB.y,aB.z,aB.w};
            float bv[8] = {bA.x,bA.y,bA.z,bA.w,bB.x,bB.y,bB.z,bB.w};
#pragma unroll
            for (int i = 0; i < 8; ++i)
#pragma unroll
                for (int j = 0; j < 8; ++j)
                    acc[i][j] = fmaf(av[i], bv[j], acc[i][j]);
        }
    }
#pragma unroll
    for (int i = 0; i < 8; ++i) {
        const int row = mt + tr*8 + i;
#pragma unroll
        for (int jq = 0; jq < 2; ++jq) {
            const int col = nt + tc*8 + jq*4;
            float4 v;
            v.x = acc[i][jq*4+0] + bias[col+0];
            v.y = acc[i][jq*4+1] + bias[col+1];
            v.z = acc[i][jq*4+2] + bias[col+2];
            v.w = acc[i][jq*4+3] + bias[col+3];
            if (relu) {
                v.x = fmaxf(v.x, 0.f); v.y = fmaxf(v.y, 0.f);
                v.z = fmaxf(v.z, 0.f); v.w = fmaxf(v.w, 0.f);
            }
            *(float4*)(C + (size_t)row * N + col) = v;
        }
    }
}

// =====================================================================
// QK^T batched GEMM: scores[zz][m][n] = sum_k Q[m][k] K[n][k]
// z = zoff + blockIdx.z -> (b = z>>1, h = z&1). M=N=512, K=256.
// =====================================================================
__global__ __launch_bounds__(256) void qk_gemm(
    const float* __restrict__ qkv, float* __restrict__ scores, int zoff)
{
    __shared__ __align__(16) float As[16][128];
    __shared__ __align__(16) float Bs[16][128];
    const int t  = threadIdx.x;
    const int nt = blockIdx.x * 128;
    const int mt = blockIdx.y * 128;
    const int zz = blockIdx.z;
    const int z  = zoff + zz;
    const int b  = z >> 1, h = z & 1;
    const float* Aq = qkv + (size_t)b*SS*E3 + h*HDD;        // Q, row stride E3
    const float* Bk = qkv + (size_t)b*SS*E3 + EE + h*HDD;   // K, row stride E3
    float* Cs = scores + (size_t)zz*SS*SS;

    const int tr = t >> 4, tc = t & 15;
    const int lr = t >> 2, lk = (t & 3) * 4;

    float acc[8][8];
#pragma unroll
    for (int i = 0; i < 8; ++i)
#pragma unroll
        for (int j = 0; j < 8; ++j) acc[i][j] = 0.f;

    for (int k0 = 0; k0 < HDD; k0 += 16) {
        float4 a0 = *(const float4*)(Aq + (size_t)(mt + lr)      * E3 + k0 + lk);
        float4 a1 = *(const float4*)(Aq + (size_t)(mt + lr + 64) * E3 + k0 + lk);
        float4 b0 = *(const float4*)(Bk + (size_t)(nt + lr)      * E3 + k0 + lk);
        float4 b1 = *(const float4*)(Bk + (size_t)(nt + lr + 64) * E3 + k0 + lk);
        __syncthreads();
        As[lk+0][lr]    = a0.x; As[lk+1][lr]    = a0.y; As[lk+2][lr]    = a0.z; As[lk+3][lr]    = a0.w;
        As[lk+0][lr+64] = a1.x; As[lk+1][lr+64] = a1.y; As[lk+2][lr+64] = a1.z; As[lk+3][lr+64] = a1.w;
        Bs[lk+0][lr]    = b0.x; Bs[lk+1][lr]    = b0.y; Bs[lk+2][lr]    = b0.z; Bs[lk+3][lr]    = b0.w;
        Bs[lk+0][lr+64] = b1.x; Bs[lk+1][lr+64] = b1.y; Bs[lk+2][lr+64] = b1.z; Bs[lk+3][lr+64] = b1.w;
        __syncthreads();
#pragma unroll
        for (int kk = 0; kk < 16; ++kk) {
            float4 aA = *(const float4*)&As[kk][tr*8];
            float4 aB = *(const float4*)&As[kk][tr*8+4];
            float4 bA = *(const float4*)&Bs[kk][tc*8];
            float4 bB = *(const float4*)&Bs[kk][tc*8+4];
            float av[8] = {aA.x,aA.y,aA.z,aA.w,aB.x,aB.y,aB.z,aB.w};
            float bv[8] = {bA.x,bA.y,bA.z,bA.w,bB.x,bB.y,bB.z,bB.w};
#pragma unroll
            for (int i = 0; i < 8; ++i)
#pragma unroll
                for (int j = 0; j < 8; ++j)
                    acc[i][j] = fmaf(av[i], bv[j], acc[i][j]);
        }
    }
#pragma unroll
    for (int i = 0; i < 8; ++i) {
        const int row = mt + tr*8 + i;
#pragma unroll
        for (int jq = 0; jq < 2; ++jq) {
            float4 v = {acc[i][jq*4+0], acc[i][jq*4+1], acc[i][jq*4+2], acc[i][jq*4+3]};
            *(float4*)(Cs + (size_t)row * SS + nt + tc*8 + jq*4) = v;
        }
    }
}

// =====================================================================
// Row softmax over scores (in place, fully normalized).
// One wave per 512-long row; 4 rows per block. nrows = 16384 per pass.
// softmax(s/16) computed as exp((s-max)*scale)/sum  (scale>0 => same max).
// =====================================================================
__global__ __launch_bounds__(256) void softmax_rows(float* __restrict__ scores)
{
    const int w    = threadIdx.x >> 6;
    const int lane = threadIdx.x & 63;
    const size_t row = (size_t)blockIdx.x * 4 + w;
    float* p = scores + row * SS + lane * 8;
    float4 v0 = *(float4*)(p);
    float4 v1 = *(float4*)(p + 4);
    const float scale = 0.0625f;
    float m = fmaxf(fmaxf(fmaxf(v0.x, v0.y), fmaxf(v0.z, v0.w)),
                    fmaxf(fmaxf(v1.x, v1.y), fmaxf(v1.z, v1.w)));
#pragma unroll
    for (int off = 32; off >= 1; off >>= 1) m = fmaxf(m, __shfl_xor(m, off));
    v0.x = __expf((v0.x - m) * scale); v0.y = __expf((v0.y - m) * scale);
    v0.z = __expf((v0.z - m) * scale); v0.w = __expf((v0.w - m) * scale);
    v1.x = __expf((v1.x - m) * scale); v1.y = __expf((v1.y - m) * scale);
    v1.z = __expf((v1.z - m) * scale); v1.w = __expf((v1.w - m) * scale);
    float sum = v0.x + v0.y + v0.z + v0.w + v1.x + v1.y + v1.z + v1.w;
#pragma unroll
    for (int off = 32; off >= 1; off >>= 1) sum += __shfl_xor(sum, off);
    float inv = 1.f / sum;
    v0.x *= inv; v0.y *= inv; v0.z *= inv; v0.w *= inv;
    v1.x *= inv; v1.y *= inv; v1.z *= inv; v1.w *= inv;
    *(float4*)(p)     = v0;
    *(float4*)(p + 4) = v1;
}

// =====================================================================
// PV batched GEMM: attn[b, m, h*256 + n] = sum_k P[zz][m][k] V[b,k,h][n]
// M=512, N=256 (2 tiles), K=512. B operand staged non-transposed.
// =====================================================================
__global__ __launch_bounds__(256) void pv_gemm(
    const float* __restrict__ scores, const float* __restrict__ qkv,
    float* __restrict__ attn, int zoff)
{
    __shared__ __align__(16) float As[16][128];
    __shared__ __align__(16) float Bs[16][128];
    const int t  = threadIdx.x;
    const int nt = blockIdx.x * 128;     // 0 or 128 within head dim
    const int mt = blockIdx.y * 128;
    const int zz = blockIdx.z;
    const int z  = zoff + zz;
    const int b  = z >> 1, h = z & 1;
    const float* P = scores + (size_t)zz*SS*SS;               // row stride SS
    const float* V = qkv + (size_t)b*SS*E3 + 2*EE + h*HDD;    // row k stride E3
    float* C = attn + (size_t)b*SS*EE + h*HDD;                // row stride EE

    const int tr = t >> 4, tc = t & 15;
    const int lr = t >> 2, lk = (t & 3) * 4;
    const int bk   = t >> 5;            // 0..7
    const int bcol = (t & 31) * 4;      // 0..124

    float acc[8][8];
#pragma unroll
    for (int i = 0; i < 8; ++i)
#pragma unroll
        for (int j = 0; j < 8; ++j) acc[i][j] = 0.f;

    for (int k0 = 0; k0 < SS; k0 += 16) {
        float4 a0 = *(const float4*)(P + (size_t)(mt + lr)      * SS + k0 + lk);
        float4 a1 = *(const float4*)(P + (size_t)(mt + lr + 64) * SS + k0 + lk);
        float4 v0 = *(const float4*)(V + (size_t)(k0 + bk)     * E3 + nt + bcol);
        float4 v1 = *(const float4*)(V + (size_t)(k0 + bk + 8) * E3 + nt + bcol);
        __syncthreads();
        As[lk+0][lr]    = a0.x; As[lk+1][lr]    = a0.y; As[lk+2][lr]    = a0.z; As[lk+3][lr]    = a0.w;
        As[lk+0][lr+64] = a1.x; As[lk+1][lr+64] = a1.y; As[lk+2][lr+64] = a1.z; As[lk+3][lr+64] = a1.w;
        *(float4*)&Bs[bk][bcol]   = v0;
        *(float4*)&Bs[bk+8][bcol] = v1;
        __syncthreads();
#pragma unroll
        for (int kk = 0; kk < 16; ++kk) {
            float4 aA = *(const float4*)&As[kk][tr*8];
            float4 aB = *(const float4*)&As[kk][tr*8+4];
            float4 bA = *(const float4*)&Bs[kk][tc*8];
            float4 bB = *(const float4*)&Bs[kk][tc*8+4];
            float av[8] = {aA.x,aA.y,aA.z,aA.w,aB.x,aB.y,aB.z,aB.w};
            float bv[8] = {bA.x,bA.y,bA.z,bA.w,bB.x,bB.y,bB.z,bB.w};
#pragma unroll
            for (int i = 0; i < 8; ++i)
#pragma unroll
                for (int j = 0; j < 8; ++j)
                    acc[i][j] = fmaf(av[i], bv[j], acc[i][j]);
        }
    }
#pragma unroll
    for (int i = 0; i < 8; ++i) {
        const int row = mt + tr*8 + i;
#pragma unroll
        for (int jq = 0; jq < 2; ++jq) {
            float4 v = {acc[i][jq*4+0], acc[i][jq*4+1], acc[i][jq*4+2], acc[i][jq*4+3]};
            *(float4*)(C + (size_t)row * EE + nt + tc*8 + jq*4) = v;
        }
    }
}

// =====================================================================
// CRF emissions: fc[row][j] = dot(dec[row], crf_w[j]) + crf_b[j]
// 192 threads = 8 rows x 24 tags. crf_w staged in LDS (padded 516).
// =====================================================================
__global__ __launch_bounds__(192) void fc_crf_kernel(
    const float* __restrict__ dec, const float* __restrict__ W,
    const float* __restrict__ bias, float* __restrict__ out)
{
    __shared__ __align__(16) float Ws[NT][516];
    for (int i = threadIdx.x; i < NT*128; i += 192) {
        int j = i >> 7, c = (i & 127) * 4;
        *(float4*)&Ws[j][c] = *(const float4*)(W + (size_t)j*EE + c);
    }
    __syncthreads();
    const int t = threadIdx.x;
    const int rloc = t / NT;
    const int j = t - rloc * NT;
    const int row = blockIdx.x * 8 + rloc;
    const float4* a = (const float4*)(dec + (size_t)row * EE);
    float acc = 0.f;
#pragma unroll 4
    for (int i = 0; i < 128; ++i) {
        float4 x = a[i];
        float4 y = *(const float4*)&Ws[j][i*4];
        acc += x.x*y.x + x.y*y.y + x.z*y.z + x.w*y.w;
    }
    out[(size_t)row * NT + j] = acc + bias[j];
}

// =====================================================================
// Merged CRF (forward + viterbi + numerator; 24 blocks x 4 waves) +
// segmentation head (blocks >= 24, 4 rows per block, MR/4 blocks).
// Single-wave CRF tasks: no s_barrier needed — wave lockstep +
// volatile LDS + wave_barrier for compiler ordering.
// =====================================================================
__global__ __launch_bounds__(256) void crf_seg_kernel(
    const float* __restrict__ fc, const int* __restrict__ labels,
    const float* __restrict__ start_t, const float* __restrict__ end_t,
    const float* __restrict__ trans, const float* __restrict__ dec,
    const float* __restrict__ ent_w, const float* __restrict__ ent_b,
    float* __restrict__ num, float* __restrict__ den,
    float* __restrict__ crf_out, float* __restrict__ segout)
{
    __shared__ float tr_s[NT*NT];
    __shared__ volatile float sc_s[4][NT];
    __shared__ unsigned char hist[4][(SS-1)*NT];

    const int blk = blockIdx.x;
    if (blk >= 24) {
        // ---------------- segmentation head: 4 rows per block -----------
        const int w    = threadIdx.x >> 6;
        const int lane = threadIdx.x & 63;
        const int row  = (blk - 24) * 4 + w;          // 0 .. MR-1
        const float4* a  = (const float4*)(dec + (size_t)row * EE);
        const float4* w0 = (const float4*)(ent_w);
        const float4* w1 = (const float4*)(ent_w + EE);
        float acc0 = 0.f, acc1 = 0.f;
#pragma unroll
        for (int i = 0; i < 2; ++i) {
            int idx = lane * 2 + i;
            float4 x = a[idx];
            float4 u = w0[idx];
            float4 v = w1[idx];
            acc0 += x.x*u.x + x.y*u.y + x.z*u.z + x.w*u.w;
            acc1 += x.x*v.x + x.y*v.y + x.z*v.z + x.w*v.w;
        }
#pragma unroll
        for (int off = 32; off >= 1; off >>= 1) {
            acc0 += __shfl_xor(acc0, off);
            acc1 += __shfl_xor(acc1, off);
        }
        if (lane == 0) {
            float l0 = acc0 + ent_b[0];
            float l1 = acc1 + ent_b[1];
            float m  = fmaxf(l0, l1);
            float lse = m + __logf(__expf(l0 - m) + __expf(l1 - m));
            segout[(size_t)row*2 + 0] = l0 - lse;
            segout[(size_t)row*2 + 1] = l1 - lse;
        }
        return;
    }

    // ---------------- CRF: 24 blocks x 4 waves = 96 single-wave tasks ----
    const int w    = threadIdx.x >> 6;
    const int lane = threadIdx.x & 63;
    const int task = blk * 4 + w;       // 0..95
    const int role = task >> 5;         // 0=forward, 1=viterbi, 2=numerator
    const int b    = task & 31;

    for (int i = threadIdx.x; i < NT*NT; i += 256) tr_s[i] = trans[i];
    __syncthreads();

    const float* fcb = fc + (size_t)b * SS * NT;

    if (role == 2) {
        // ---- numerator ----
        float acc = 0.f;
        for (int s = 1 + lane; s < SS; s += 64) {
            int prev = labels[b*SS + s - 1];
            int cur  = labels[b*SS + s];
            acc += trans[prev*NT + cur] + fcb[(size_t)s*NT + cur];
        }
        if (lane == 0) {
            int l0 = labels[b*SS];
            acc += start_t[l0] + fcb[l0] + end_t[labels[b*SS + SS - 1]];
        }
#pragma unroll
        for (int off = 32; off >= 1; off >>= 1) acc += __shfl_xor(acc, off);
        if (lane == 0) num[b] = acc;
        return;
    }

    volatile float* sc = sc_s[w];
    const int tj = (lane < NT) ? lane : 0;
    if (lane < NT) sc[lane] = start_t[lane] + fcb[lane];
    WAVE_BAR();

    if (role == 0) {
        // ---- forward (log-normalizer) ----
        float em_next = fcb[NT + tj];
        for (int s = 1; s < SS; ++s) {
            float em = em_next;
            int snx = (s + 1 < SS) ? s + 1 : s;
            em_next = fcb[(size_t)snx * NT + tj];     // prefetch next step
            float m = sc[0];
#pragma unroll
            for (int i = 1; i < NT; ++i) m = fmaxf(m, sc[i]);
            float sum = 0.f;
#pragma unroll
            for (int i = 0; i < NT; ++i) sum += __expf(sc[i] - m + tr_s[i*NT + tj]);
            float nxt = m + __logf(sum) + em;
            WAVE_BAR();
            if (lane < NT) sc[lane] = nxt;
            WAVE_BAR();
        }
        float m2 = sc[0] + end_t[0];
#pragma unroll
        for (int i = 1; i < NT; ++i) m2 = fmaxf(m2, sc[i] + end_t[i]);
        float s2 = 0.f;
#pragma unroll
        for (int i = 0; i < NT; ++i) s2 += __expf(sc[i] + end_t[i] - m2);
        if (lane == 0) den[b] = m2 + __logf(s2);
    } else {
        // ---- viterbi ----
        unsigned char* hw = hist[w];
        float em_next = fcb[NT + tj];
        for (int s = 1; s < SS; ++s) {
            float em = em_next;
            int snx = (s + 1 < SS) ? s + 1 : s;
            em_next = fcb[(size_t)snx * NT + tj];
            float best = sc[0] + tr_s[tj];
            int arg = 0;
#pragma unroll
            for (int i = 1; i < NT; ++i) {
                float v = sc[i] + tr_s[i*NT + tj];
                if (v > best) { best = v; arg = i; }
            }
            WAVE_BAR();
            if (lane < NT) { sc[lane] = best + em; hw[(s-1)*NT + lane] = (unsigned char)arg; }
            WAVE_BAR();
        }
        if (lane == 0) {
            int tag = 0;
            float bv = sc[0] + end_t[0];
            for (int i = 1; i < NT; ++i) {
                float v = sc[i] + end_t[i];
                if (v > bv) { bv = v; tag = i; }
            }
            crf_out[(size_t)b*SS + SS - 1] = (float)tag;
            for (int s = SS - 2; s >= 0; --s) {
                tag = hw[s*NT + tag];
                crf_out[(size_t)b*SS + s] = (float)tag;
            }
        }
    }
}

// =====================================================================
// Final scalar: -llh = -( sum_b(num[b]-den[b]) / 16384 )
// =====================================================================
__global__ __launch_bounds__(64) void llh_kernel(
    const float* __restrict__ num, const float* __restrict__ den,
    float* __restrict__ out)
{
    int t = threadIdx.x;
    float v = (t < BB) ? (num[t] - den[t]) : 0.f;
#pragma unroll
    for (int off = 32; off >= 1; off >>= 1) v += __shfl_xor(v, off);
    if (t == 0) out[(size_t)MR * 3] = -(v / (float)MR);
}

extern "C" void kernel_launch(void* const* d_in, const int* in_sizes, int n_in,
                              void* d_out, int out_size, void* d_ws, size_t ws_size,
                              hipStream_t stream) {
    const float* enc     = (const float*)d_in[0];
    const int*   labels  = (const int*)  d_in[1];
    // d_in[2] = mask (all ones by construction; unused)
    const float* Win     = (const float*)d_in[3];
    const float* bin     = (const float*)d_in[4];
    const float* Wout    = (const float*)d_in[5];
    const float* bout    = (const float*)d_in[6];
    const float* crf_w   = (const float*)d_in[7];
    const float* crf_b   = (const float*)d_in[8];
    const float* start_t = (const float*)d_in[9];
    const float* end_t   = (const float*)d_in[10];
    const float* trans   = (const float*)d_in[11];
    const float* ent_w   = (const float*)d_in[12];
    const float* ent_b   = (const float*)d_in[13];
    float* out = (float*)d_out;

    // Workspace layout — identical footprint to the proven round-1 layout
    // (169.4 MB). The 33.5MB scores-half buffer exactly aliases dec
    // (both 8,388,608 floats); scores are dead before dec is written.
    float* ws   = (float*)d_ws;
    float* qkv  = ws;                                 // 16384*1536
    float* attn = qkv  + (size_t)MR * E3;             // 16384*512
    float* big  = attn + (size_t)MR * EE;             // 8,388,608 floats
    float* sch  = big;                                // scores half: 32*512*512
    float* dec  = big;                                // dec aliases scores
    float* fc   = big  + (size_t)MR * EE;             // 16384*24
    float* num  = fc   + (size_t)MR * NT;             // 32
    float* den  = num  + BB;                          // 32

    dim3 blk(256);
    // 1. qkv = enc @ Win^T + bin
    gemm_bt128<<<dim3(E3/128, MR/128), blk, 0, stream>>>(enc, Win, bin, qkv, MR, E3, EE, 0);
    // 2. attention in two z-passes of 32 (b,h) pairs each
    for (int p = 0; p < 2; ++p) {
        int zoff = p * 32;
        qk_gemm<<<dim3(SS/128, SS/128, 32), blk, 0, stream>>>(qkv, sch, zoff);
        softmax_rows<<<(32*SS)/4, blk, 0, stream>>>(sch);
        pv_gemm<<<dim3(HDD/128, SS/128, 32), blk, 0, stream>>>(sch, qkv, attn, zoff);
    }
    // 3. dec = relu(attn @ Wout^T + bout)   (overwrites scores region)
    gemm_bt128<<<dim3(EE/128, MR/128), blk, 0, stream>>>(attn, Wout, bout, dec, MR, EE, EE, 1);
    // 4. fc emissions
    fc_crf_kernel<<<MR/8, dim3(192), 0, stream>>>(dec, crf_w, crf_b, fc);
    // 5. CRF (forward+viterbi+numerator) + seg head merged (MR/4 seg blocks!)
    crf_seg_kernel<<<24 + MR/4, blk, 0, stream>>>(
        fc, labels, start_t, end_t, trans, dec, ent_w, ent_b,
        num, den, out, out + MR);
    // 6. -llh scalar -> d_out[49152]
    llh_kernel<<<1, 64, 0, stream>>>(num, den, out);
}

// Round 4
// 1123.203 us; speedup vs baseline: 1.4547x; 1.4547x over previous
//
#include <hip/hip_runtime.h>

#define BB 32
#define SS 512
#define EE 512
#define NHH 2
#define HDD 256
#define E3 1536
#define NT 24
#define MR (BB*SS)   // 16384

#define WAVE_BAR() __builtin_amdgcn_wave_barrier()

// =====================================================================
// GEMM: C[M][N] = A[M][K] . B[N][K]^T + bias[N], optional ReLU.
// 128x128 block tile, 256 threads, 8x8 per thread, BK=16.
// =====================================================================
__global__ __launch_bounds__(256) void gemm_bt128(
    const float* __restrict__ A, const float* __restrict__ Bm,
    const float* __restrict__ bias, float* __restrict__ C,
    int M, int N, int K, int relu)
{
    __shared__ __align__(16) float As[16][128];
    __shared__ __align__(16) float Bs[16][128];
    const int t  = threadIdx.x;
    const int mt = blockIdx.y * 128;
    const int nt = blockIdx.x * 128;
    const int tr = t >> 4;          // 0..15
    const int tc = t & 15;          // 0..15
    const int lr = t >> 2;          // 0..63
    const int lk = (t & 3) * 4;     // 0,4,8,12

    float acc[8][8];
#pragma unroll
    for (int i = 0; i < 8; ++i)
#pragma unroll
        for (int j = 0; j < 8; ++j) acc[i][j] = 0.f;

    for (int k0 = 0; k0 < K; k0 += 16) {
        float4 a0 = *(const float4*)(A  + (size_t)(mt + lr)      * K + k0 + lk);
        float4 a1 = *(const float4*)(A  + (size_t)(mt + lr + 64) * K + k0 + lk);
        float4 b0 = *(const float4*)(Bm + (size_t)(nt + lr)      * K + k0 + lk);
        float4 b1 = *(const float4*)(Bm + (size_t)(nt + lr + 64) * K + k0 + lk);
        __syncthreads();
        As[lk+0][lr]    = a0.x; As[lk+1][lr]    = a0.y; As[lk+2][lr]    = a0.z; As[lk+3][lr]    = a0.w;
        As[lk+0][lr+64] = a1.x; As[lk+1][lr+64] = a1.y; As[lk+2][lr+64] = a1.z; As[lk+3][lr+64] = a1.w;
        Bs[lk+0][lr]    = b0.x; Bs[lk+1][lr]    = b0.y; Bs[lk+2][lr]    = b0.z; Bs[lk+3][lr]    = b0.w;
        Bs[lk+0][lr+64] = b1.x; Bs[lk+1][lr+64] = b1.y; Bs[lk+2][lr+64] = b1.z; Bs[lk+3][lr+64] = b1.w;
        __syncthreads();
#pragma unroll
        for (int kk = 0; kk < 16; ++kk) {
            float4 aA = *(const float4*)&As[kk][tr*8];
            float4 aB = *(const float4*)&As[kk][tr*8+4];
            float4 bA = *(const float4*)&Bs[kk][tc*8];
            float4 bB = *(const float4*)&Bs[kk][tc*8+4];
            float av[8] = {aA.x,aA.y,aA.z,aA.w,aB.x,aB.y,aB.z,aB.w};
            float bv[8] = {bA.x,bA.y,bA.z,bA.w,bB.x,bB.y,bB.z,bB.w};
#pragma unroll
            for (int i = 0; i < 8; ++i)
#pragma unroll
                for (int j = 0; j < 8; ++j)
                    acc[i][j] = fmaf(av[i], bv[j], acc[i][j]);
        }
    }
#pragma unroll
    for (int i = 0; i < 8; ++i) {
        const int row = mt + tr*8 + i;
#pragma unroll
        for (int jq = 0; jq < 2; ++jq) {
            const int col = nt + tc*8 + jq*4;
            float4 v;
            v.x = acc[i][jq*4+0] + bias[col+0];
            v.y = acc[i][jq*4+1] + bias[col+1];
            v.z = acc[i][jq*4+2] + bias[col+2];
            v.w = acc[i][jq*4+3] + bias[col+3];
            if (relu) {
                v.x = fmaxf(v.x, 0.f); v.y = fmaxf(v.y, 0.f);
                v.z = fmaxf(v.z, 0.f); v.w = fmaxf(v.w, 0.f);
            }
            *(float4*)(C + (size_t)row * N + col) = v;
        }
    }
}

// =====================================================================
// QK^T batched GEMM: scores[zz][m][n] = sum_k Q[m][k] K[n][k]
// z = zoff + blockIdx.z -> (b = z>>1, h = z&1). M=N=512, K=256.
// =====================================================================
__global__ __launch_bounds__(256) void qk_gemm(
    const float* __restrict__ qkv, float* __restrict__ scores, int zoff)
{
    __shared__ __align__(16) float As[16][128];
    __shared__ __align__(16) float Bs[16][128];
    const int t  = threadIdx.x;
    const int nt = blockIdx.x * 128;
    const int mt = blockIdx.y * 128;
    const int zz = blockIdx.z;
    const int z  = zoff + zz;
    const int b  = z >> 1, h = z & 1;
    const float* Aq = qkv + (size_t)b*SS*E3 + h*HDD;        // Q, row stride E3
    const float* Bk = qkv + (size_t)b*SS*E3 + EE + h*HDD;   // K, row stride E3
    float* Cs = scores + (size_t)zz*SS*SS;

    const int tr = t >> 4, tc = t & 15;
    const int lr = t >> 2, lk = (t & 3) * 4;

    float acc[8][8];
#pragma unroll
    for (int i = 0; i < 8; ++i)
#pragma unroll
        for (int j = 0; j < 8; ++j) acc[i][j] = 0.f;

    for (int k0 = 0; k0 < HDD; k0 += 16) {
        float4 a0 = *(const float4*)(Aq + (size_t)(mt + lr)      * E3 + k0 + lk);
        float4 a1 = *(const float4*)(Aq + (size_t)(mt + lr + 64) * E3 + k0 + lk);
        float4 b0 = *(const float4*)(Bk + (size_t)(nt + lr)      * E3 + k0 + lk);
        float4 b1 = *(const float4*)(Bk + (size_t)(nt + lr + 64) * E3 + k0 + lk);
        __syncthreads();
        As[lk+0][lr]    = a0.x; As[lk+1][lr]    = a0.y; As[lk+2][lr]    = a0.z; As[lk+3][lr]    = a0.w;
        As[lk+0][lr+64] = a1.x; As[lk+1][lr+64] = a1.y; As[lk+2][lr+64] = a1.z; As[lk+3][lr+64] = a1.w;
        Bs[lk+0][lr]    = b0.x; Bs[lk+1][lr]    = b0.y; Bs[lk+2][lr]    = b0.z; Bs[lk+3][lr]    = b0.w;
        Bs[lk+0][lr+64] = b1.x; Bs[lk+1][lr+64] = b1.y; Bs[lk+2][lr+64] = b1.z; Bs[lk+3][lr+64] = b1.w;
        __syncthreads();
#pragma unroll
        for (int kk = 0; kk < 16; ++kk) {
            float4 aA = *(const float4*)&As[kk][tr*8];
            float4 aB = *(const float4*)&As[kk][tr*8+4];
            float4 bA = *(const float4*)&Bs[kk][tc*8];
            float4 bB = *(const float4*)&Bs[kk][tc*8+4];
            float av[8] = {aA.x,aA.y,aA.z,aA.w,aB.x,aB.y,aB.z,aB.w};
            float bv[8] = {bA.x,bA.y,bA.z,bA.w,bB.x,bB.y,bB.z,bB.w};
#pragma unroll
            for (int i = 0; i < 8; ++i)
#pragma unroll
                for (int j = 0; j < 8; ++j)
                    acc[i][j] = fmaf(av[i], bv[j], acc[i][j]);
        }
    }
#pragma unroll
    for (int i = 0; i < 8; ++i) {
        const int row = mt + tr*8 + i;
#pragma unroll
        for (int jq = 0; jq < 2; ++jq) {
            float4 v = {acc[i][jq*4+0], acc[i][jq*4+1], acc[i][jq*4+2], acc[i][jq*4+3]};
            *(float4*)(Cs + (size_t)row * SS + nt + tc*8 + jq*4) = v;
        }
    }
}

// =====================================================================
// Row softmax over scores (in place, fully normalized).
// =====================================================================
__global__ __launch_bounds__(256) void softmax_rows(float* __restrict__ scores)
{
    const int w    = threadIdx.x >> 6;
    const int lane = threadIdx.x & 63;
    const size_t row = (size_t)blockIdx.x * 4 + w;
    float* p = scores + row * SS + lane * 8;
    float4 v0 = *(float4*)(p);
    float4 v1 = *(float4*)(p + 4);
    const float scale = 0.0625f;
    float m = fmaxf(fmaxf(fmaxf(v0.x, v0.y), fmaxf(v0.z, v0.w)),
                    fmaxf(fmaxf(v1.x, v1.y), fmaxf(v1.z, v1.w)));
#pragma unroll
    for (int off = 32; off >= 1; off >>= 1) m = fmaxf(m, __shfl_xor(m, off));
    v0.x = __expf((v0.x - m) * scale); v0.y = __expf((v0.y - m) * scale);
    v0.z = __expf((v0.z - m) * scale); v0.w = __expf((v0.w - m) * scale);
    v1.x = __expf((v1.x - m) * scale); v1.y = __expf((v1.y - m) * scale);
    v1.z = __expf((v1.z - m) * scale); v1.w = __expf((v1.w - m) * scale);
    float sum = v0.x + v0.y + v0.z + v0.w + v1.x + v1.y + v1.z + v1.w;
#pragma unroll
    for (int off = 32; off >= 1; off >>= 1) sum += __shfl_xor(sum, off);
    float inv = 1.f / sum;
    v0.x *= inv; v0.y *= inv; v0.z *= inv; v0.w *= inv;
    v1.x *= inv; v1.y *= inv; v1.z *= inv; v1.w *= inv;
    *(float4*)(p)     = v0;
    *(float4*)(p + 4) = v1;
}

// =====================================================================
// PV batched GEMM: attn[b, m, h*256 + n] = sum_k P[zz][m][k] V[b,k,h][n]
// =====================================================================
__global__ __launch_bounds__(256) void pv_gemm(
    const float* __restrict__ scores, const float* __restrict__ qkv,
    float* __restrict__ attn, int zoff)
{
    __shared__ __align__(16) float As[16][128];
    __shared__ __align__(16) float Bs[16][128];
    const int t  = threadIdx.x;
    const int nt = blockIdx.x * 128;     // 0 or 128 within head dim
    const int mt = blockIdx.y * 128;
    const int zz = blockIdx.z;
    const int z  = zoff + zz;
    const int b  = z >> 1, h = z & 1;
    const float* P = scores + (size_t)zz*SS*SS;               // row stride SS
    const float* V = qkv + (size_t)b*SS*E3 + 2*EE + h*HDD;    // row k stride E3
    float* C = attn + (size_t)b*SS*EE + h*HDD;                // row stride EE

    const int tr = t >> 4, tc = t & 15;
    const int lr = t >> 2, lk = (t & 3) * 4;
    const int bk   = t >> 5;            // 0..7
    const int bcol = (t & 31) * 4;      // 0..124

    float acc[8][8];
#pragma unroll
    for (int i = 0; i < 8; ++i)
#pragma unroll
        for (int j = 0; j < 8; ++j) acc[i][j] = 0.f;

    for (int k0 = 0; k0 < SS; k0 += 16) {
        float4 a0 = *(const float4*)(P + (size_t)(mt + lr)      * SS + k0 + lk);
        float4 a1 = *(const float4*)(P + (size_t)(mt + lr + 64) * SS + k0 + lk);
        float4 v0 = *(const float4*)(V + (size_t)(k0 + bk)     * E3 + nt + bcol);
        float4 v1 = *(const float4*)(V + (size_t)(k0 + bk + 8) * E3 + nt + bcol);
        __syncthreads();
        As[lk+0][lr]    = a0.x; As[lk+1][lr]    = a0.y; As[lk+2][lr]    = a0.z; As[lk+3][lr]    = a0.w;
        As[lk+0][lr+64] = a1.x; As[lk+1][lr+64] = a1.y; As[lk+2][lr+64] = a1.z; As[lk+3][lr+64] = a1.w;
        *(float4*)&Bs[bk][bcol]   = v0;
        *(float4*)&Bs[bk+8][bcol] = v1;
        __syncthreads();
#pragma unroll
        for (int kk = 0; kk < 16; ++kk) {
            float4 aA = *(const float4*)&As[kk][tr*8];
            float4 aB = *(const float4*)&As[kk][tr*8+4];
            float4 bA = *(const float4*)&Bs[kk][tc*8];
            float4 bB = *(const float4*)&Bs[kk][tc*8+4];
            float av[8] = {aA.x,aA.y,aA.z,aA.w,aB.x,aB.y,aB.z,aB.w};
            float bv[8] = {bA.x,bA.y,bA.z,bA.w,bB.x,bB.y,bB.z,bB.w};
#pragma unroll
            for (int i = 0; i < 8; ++i)
#pragma unroll
                for (int j = 0; j < 8; ++j)
                    acc[i][j] = fmaf(av[i], bv[j], acc[i][j]);
        }
    }
#pragma unroll
    for (int i = 0; i < 8; ++i) {
        const int row = mt + tr*8 + i;
#pragma unroll
        for (int jq = 0; jq < 2; ++jq) {
            float4 v = {acc[i][jq*4+0], acc[i][jq*4+1], acc[i][jq*4+2], acc[i][jq*4+3]};
            *(float4*)(C + (size_t)row * EE + nt + tc*8 + jq*4) = v;
        }
    }
}

// =====================================================================
// CRF emissions: fc[row][j] = dot(dec[row], crf_w[j]) + crf_b[j]
// =====================================================================
__global__ __launch_bounds__(192) void fc_crf_kernel(
    const float* __restrict__ dec, const float* __restrict__ W,
    const float* __restrict__ bias, float* __restrict__ out)
{
    __shared__ __align__(16) float Ws[NT][516];
    for (int i = threadIdx.x; i < NT*128; i += 192) {
        int j = i >> 7, c = (i & 127) * 4;
        *(float4*)&Ws[j][c] = *(const float4*)(W + (size_t)j*EE + c);
    }
    __syncthreads();
    const int t = threadIdx.x;
    const int rloc = t / NT;
    const int j = t - rloc * NT;
    const int row = blockIdx.x * 8 + rloc;
    const float4* a = (const float4*)(dec + (size_t)row * EE);
    float acc = 0.f;
#pragma unroll 4
    for (int i = 0; i < 128; ++i) {
        float4 x = a[i];
        float4 y = *(const float4*)&Ws[j][i*4];
        acc += x.x*y.x + x.y*y.y + x.z*y.z + x.w*y.w;
    }
    out[(size_t)row * NT + j] = acc + bias[j];
}

// =====================================================================
// Merged CRF + seg. CRF recursion is now register/shuffle-based:
// lane j holds sc[j]; per step, 24 independent __shfl broadcasts +
// register trans column + explicit reduction trees. NO LDS in the
// recursion (round-3's volatile-LDS serialization was 3750 cyc/step).
// Viterbi history: volatile LDS byte WRITES only (no loop reads).
// =====================================================================
__global__ __launch_bounds__(256) void crf_seg_kernel(
    const float* __restrict__ fc, const int* __restrict__ labels,
    const float* __restrict__ start_t, const float* __restrict__ end_t,
    const float* __restrict__ trans, const float* __restrict__ dec,
    const float* __restrict__ ent_w, const float* __restrict__ ent_b,
    float* __restrict__ num, float* __restrict__ den,
    float* __restrict__ crf_out, float* __restrict__ segout)
{
    __shared__ unsigned char hist[4][(SS-1)*NT];

    const int blk = blockIdx.x;
    if (blk >= 24) {
        // ---------------- segmentation head: 4 rows per block -----------
        const int w    = threadIdx.x >> 6;
        const int lane = threadIdx.x & 63;
        const int row  = (blk - 24) * 4 + w;          // 0 .. MR-1
        const float4* a  = (const float4*)(dec + (size_t)row * EE);
        const float4* w0 = (const float4*)(ent_w);
        const float4* w1 = (const float4*)(ent_w + EE);
        float acc0 = 0.f, acc1 = 0.f;
#pragma unroll
        for (int i = 0; i < 2; ++i) {
            int idx = lane * 2 + i;
            float4 x = a[idx];
            float4 u = w0[idx];
            float4 v = w1[idx];
            acc0 += x.x*u.x + x.y*u.y + x.z*u.z + x.w*u.w;
            acc1 += x.x*v.x + x.y*v.y + x.z*v.z + x.w*v.w;
        }
#pragma unroll
        for (int off = 32; off >= 1; off >>= 1) {
            acc0 += __shfl_xor(acc0, off);
            acc1 += __shfl_xor(acc1, off);
        }
        if (lane == 0) {
            float l0 = acc0 + ent_b[0];
            float l1 = acc1 + ent_b[1];
            float m  = fmaxf(l0, l1);
            float lse = m + __logf(__expf(l0 - m) + __expf(l1 - m));
            segout[(size_t)row*2 + 0] = l0 - lse;
            segout[(size_t)row*2 + 1] = l1 - lse;
        }
        return;
    }

    // ---------------- CRF: 24 blocks x 4 waves = 96 single-wave tasks ----
    const int w    = threadIdx.x >> 6;
    const int lane = threadIdx.x & 63;
    const int task = blk * 4 + w;       // 0..95
    const int role = task >> 5;         // 0=forward, 1=viterbi, 2=numerator
    const int b    = task & 31;
    const float* fcb = fc + (size_t)b * SS * NT;

    if (role == 2) {
        // ---- numerator ----
        float acc = 0.f;
        for (int s = 1 + lane; s < SS; s += 64) {
            int prev = labels[b*SS + s - 1];
            int cur  = labels[b*SS + s];
            acc += trans[prev*NT + cur] + fcb[(size_t)s*NT + cur];
        }
        if (lane == 0) {
            int l0 = labels[b*SS];
            acc += start_t[l0] + fcb[l0] + end_t[labels[b*SS + SS - 1]];
        }
#pragma unroll
        for (int off = 32; off >= 1; off >>= 1) acc += __shfl_xor(acc, off);
        if (lane == 0) num[b] = acc;
        return;
    }

    // lane j owns destination tag j; trC[i] = trans[i][j] (source i -> j)
    const int j = (lane < NT) ? lane : 0;
    float trC[NT];
#pragma unroll
    for (int i = 0; i < NT; ++i) trC[i] = trans[i*NT + j];
    float sc = start_t[j] + fcb[j];

    if (role == 0) {
        // ---- forward (log-normalizer) ----
        float em_next = fcb[NT + j];
        for (int s = 1; s < SS; ++s) {
            float em = em_next;
            int snx = (s + 1 < SS) ? s + 1 : s;
            em_next = fcb[(size_t)snx * NT + j];     // prefetch next step
            float tv[NT];
#pragma unroll
            for (int i = 0; i < NT; ++i) tv[i] = __shfl(sc, i) + trC[i];
            float mx[NT];
#pragma unroll
            for (int i = 0; i < NT; ++i) mx[i] = tv[i];
#pragma unroll
            for (int st = 1; st < NT; st <<= 1)
#pragma unroll
                for (int i = 0; i + st < NT; i += 2*st)
                    mx[i] = fmaxf(mx[i], mx[i+st]);
            const float m = mx[0];
            float ev[NT];
#pragma unroll
            for (int i = 0; i < NT; ++i) ev[i] = __expf(tv[i] - m);
#pragma unroll
            for (int st = 1; st < NT; st <<= 1)
#pragma unroll
                for (int i = 0; i + st < NT; i += 2*st)
                    ev[i] += ev[i+st];
            sc = m + __logf(ev[0]) + em;
        }
        float v = (lane < NT) ? sc + end_t[j] : -1e30f;
        float m2 = v;
#pragma unroll
        for (int off = 32; off >= 1; off >>= 1) m2 = fmaxf(m2, __shfl_xor(m2, off));
        float e = (lane < NT) ? __expf(v - m2) : 0.f;
#pragma unroll
        for (int off = 32; off >= 1; off >>= 1) e += __shfl_xor(e, off);
        if (lane == 0) den[b] = m2 + __logf(e);
    } else {
        // ---- viterbi ----
        volatile unsigned char* hw = hist[w];
        float em_next = fcb[NT + j];
        for (int s = 1; s < SS; ++s) {
            float em = em_next;
            int snx = (s + 1 < SS) ? s + 1 : s;
            em_next = fcb[(size_t)snx * NT + j];
            float tv[NT]; int ti[NT];
#pragma unroll
            for (int i = 0; i < NT; ++i) { tv[i] = __shfl(sc, i) + trC[i]; ti[i] = i; }
            // first-tie argmax tree: lower index wins on equality
#pragma unroll
            for (int st = 1; st < NT; st <<= 1)
#pragma unroll
                for (int i = 0; i + st < NT; i += 2*st)
                    if (tv[i+st] > tv[i]) { tv[i] = tv[i+st]; ti[i] = ti[i+st]; }
            sc = tv[0] + em;
            if (lane < NT) hw[(s-1)*NT + lane] = (unsigned char)ti[0];
        }
        // final argmax over lanes (first-tie, lowest lane wins)
        float bv = (lane < NT) ? sc + end_t[j] : -1e30f;
        int bi = (lane < NT) ? lane : NT;
#pragma unroll
        for (int off = 32; off >= 1; off >>= 1) {
            float ov = __shfl_xor(bv, off);
            int   oi = __shfl_xor(bi, off);
            if (ov > bv || (ov == bv && oi < bi)) { bv = ov; bi = oi; }
        }
        WAVE_BAR();
        if (lane == 0) {
            int tag = bi;
            crf_out[(size_t)b*SS + SS - 1] = (float)tag;
            for (int s = SS - 2; s >= 0; --s) {
                tag = hw[s*NT + tag];
                crf_out[(size_t)b*SS + s] = (float)tag;
            }
        }
    }
}

// =====================================================================
// Final scalar: -llh = -( sum_b(num[b]-den[b]) / 16384 )
// =====================================================================
__global__ __launch_bounds__(64) void llh_kernel(
    const float* __restrict__ num, const float* __restrict__ den,
    float* __restrict__ out)
{
    int t = threadIdx.x;
    float v = (t < BB) ? (num[t] - den[t]) : 0.f;
#pragma unroll
    for (int off = 32; off >= 1; off >>= 1) v += __shfl_xor(v, off);
    if (t == 0) out[(size_t)MR * 3] = -(v / (float)MR);
}

extern "C" void kernel_launch(void* const* d_in, const int* in_sizes, int n_in,
                              void* d_out, int out_size, void* d_ws, size_t ws_size,
                              hipStream_t stream) {
    const float* enc     = (const float*)d_in[0];
    const int*   labels  = (const int*)  d_in[1];
    // d_in[2] = mask (all ones by construction; unused)
    const float* Win     = (const float*)d_in[3];
    const float* bin     = (const float*)d_in[4];
    const float* Wout    = (const float*)d_in[5];
    const float* bout    = (const float*)d_in[6];
    const float* crf_w   = (const float*)d_in[7];
    const float* crf_b   = (const float*)d_in[8];
    const float* start_t = (const float*)d_in[9];
    const float* end_t   = (const float*)d_in[10];
    const float* trans   = (const float*)d_in[11];
    const float* ent_w   = (const float*)d_in[12];
    const float* ent_b   = (const float*)d_in[13];
    float* out = (float*)d_out;

    // Workspace layout — scores half (33.5 MB) aliases dec; scores are
    // dead before dec is written.
    float* ws   = (float*)d_ws;
    float* qkv  = ws;                                 // 16384*1536
    float* attn = qkv  + (size_t)MR * E3;             // 16384*512
    float* big  = attn + (size_t)MR * EE;             // 8,388,608 floats
    float* sch  = big;                                // scores half: 32*512*512
    float* dec  = big;                                // dec aliases scores
    float* fc   = big  + (size_t)MR * EE;             // 16384*24
    float* num  = fc   + (size_t)MR * NT;             // 32
    float* den  = num  + BB;                          // 32

    dim3 blk(256);
    // 1. qkv = enc @ Win^T + bin
    gemm_bt128<<<dim3(E3/128, MR/128), blk, 0, stream>>>(enc, Win, bin, qkv, MR, E3, EE, 0);
    // 2. attention in two z-passes of 32 (b,h) pairs each
    for (int p = 0; p < 2; ++p) {
        int zoff = p * 32;
        qk_gemm<<<dim3(SS/128, SS/128, 32), blk, 0, stream>>>(qkv, sch, zoff);
        softmax_rows<<<(32*SS)/4, blk, 0, stream>>>(sch);
        pv_gemm<<<dim3(HDD/128, SS/128, 32), blk, 0, stream>>>(sch, qkv, attn, zoff);
    }
    // 3. dec = relu(attn @ Wout^T + bout)   (overwrites scores region)
    gemm_bt128<<<dim3(EE/128, MR/128), blk, 0, stream>>>(attn, Wout, bout, dec, MR, EE, EE, 1);
    // 4. fc emissions
    fc_crf_kernel<<<MR/8, dim3(192), 0, stream>>>(dec, crf_w, crf_b, fc);
    // 5. CRF (forward+viterbi+numerator) + seg head merged
    crf_seg_kernel<<<24 + MR/4, blk, 0, stream>>>(
        fc, labels, start_t, end_t, trans, dec, ent_w, ent_b,
        num, den, out, out + MR);
    // 6. -llh scalar -> d_out[49152]
    llh_kernel<<<1, 64, 0, stream>>>(num, den, out);
}

// Round 5
// 1050.513 us; speedup vs baseline: 1.5553x; 1.0692x over previous
//
#include <hip/hip_runtime.h>

#define BB 32
#define SS 512
#define EE 512
#define NHH 2
#define HDD 256
#define E3 1536
#define NT 24
#define MR (BB*SS)   // 16384

#define WAVE_BAR() __builtin_amdgcn_wave_barrier()

// Fragment row/col map: thread owns rows {tr*4..+3, 64+tr*4..+3},
// cols {tc*4..+3, 64+tc*4..+3}. 4-float spans -> LDS bank stride 4 ->
// max 2-way aliasing (free). LDS rows padded 128->132 so the staging
// writes are also exactly 2-way.

// =====================================================================
// GEMM: C[M][N] = A[M][K] . B[N][K]^T + bias[N], optional ReLU.
// 128x128 block tile, 256 threads, 8x8 per thread, BK=16.
// =====================================================================
__global__ __launch_bounds__(256) void gemm_bt128(
    const float* __restrict__ A, const float* __restrict__ Bm,
    const float* __restrict__ bias, float* __restrict__ C,
    int M, int N, int K, int relu)
{
    __shared__ __align__(16) float As[16][132];
    __shared__ __align__(16) float Bs[16][132];
    const int t  = threadIdx.x;
    const int mt = blockIdx.y * 128;
    const int nt = blockIdx.x * 128;
    const int tr = t >> 4;          // 0..15
    const int tc = t & 15;          // 0..15
    const int lr = t >> 2;          // 0..63
    const int lk = (t & 3) * 4;     // 0,4,8,12

    float acc[8][8];
#pragma unroll
    for (int i = 0; i < 8; ++i)
#pragma unroll
        for (int j = 0; j < 8; ++j) acc[i][j] = 0.f;

    for (int k0 = 0; k0 < K; k0 += 16) {
        float4 a0 = *(const float4*)(A  + (size_t)(mt + lr)      * K + k0 + lk);
        float4 a1 = *(const float4*)(A  + (size_t)(mt + lr + 64) * K + k0 + lk);
        float4 b0 = *(const float4*)(Bm + (size_t)(nt + lr)      * K + k0 + lk);
        float4 b1 = *(const float4*)(Bm + (size_t)(nt + lr + 64) * K + k0 + lk);
        __syncthreads();
        As[lk+0][lr]    = a0.x; As[lk+1][lr]    = a0.y; As[lk+2][lr]    = a0.z; As[lk+3][lr]    = a0.w;
        As[lk+0][lr+64] = a1.x; As[lk+1][lr+64] = a1.y; As[lk+2][lr+64] = a1.z; As[lk+3][lr+64] = a1.w;
        Bs[lk+0][lr]    = b0.x; Bs[lk+1][lr]    = b0.y; Bs[lk+2][lr]    = b0.z; Bs[lk+3][lr]    = b0.w;
        Bs[lk+0][lr+64] = b1.x; Bs[lk+1][lr+64] = b1.y; Bs[lk+2][lr+64] = b1.z; Bs[lk+3][lr+64] = b1.w;
        __syncthreads();
#pragma unroll
        for (int kk = 0; kk < 16; ++kk) {
            float4 aA = *(const float4*)&As[kk][tr*4];
            float4 aB = *(const float4*)&As[kk][64 + tr*4];
            float4 bA = *(const float4*)&Bs[kk][tc*4];
            float4 bB = *(const float4*)&Bs[kk][64 + tc*4];
            float av[8] = {aA.x,aA.y,aA.z,aA.w,aB.x,aB.y,aB.z,aB.w};
            float bv[8] = {bA.x,bA.y,bA.z,bA.w,bB.x,bB.y,bB.z,bB.w};
#pragma unroll
            for (int i = 0; i < 8; ++i)
#pragma unroll
                for (int j = 0; j < 8; ++j)
                    acc[i][j] = fmaf(av[i], bv[j], acc[i][j]);
        }
    }
#pragma unroll
    for (int i = 0; i < 8; ++i) {
        const int row = mt + ((i < 4) ? (tr*4 + i) : (64 + tr*4 + (i - 4)));
#pragma unroll
        for (int jh = 0; jh < 2; ++jh) {
            const int col = nt + jh*64 + tc*4;
            float4 v;
            v.x = acc[i][jh*4+0] + bias[col+0];
            v.y = acc[i][jh*4+1] + bias[col+1];
            v.z = acc[i][jh*4+2] + bias[col+2];
            v.w = acc[i][jh*4+3] + bias[col+3];
            if (relu) {
                v.x = fmaxf(v.x, 0.f); v.y = fmaxf(v.y, 0.f);
                v.z = fmaxf(v.z, 0.f); v.w = fmaxf(v.w, 0.f);
            }
            *(float4*)(C + (size_t)row * N + col) = v;
        }
    }
}

// =====================================================================
// QK^T batched GEMM: scores[zz][m][n] = sum_k Q[m][k] K[n][k]
// z = zoff + blockIdx.z -> (b = z>>1, h = z&1). M=N=512, K=256.
// =====================================================================
__global__ __launch_bounds__(256) void qk_gemm(
    const float* __restrict__ qkv, float* __restrict__ scores, int zoff)
{
    __shared__ __align__(16) float As[16][132];
    __shared__ __align__(16) float Bs[16][132];
    const int t  = threadIdx.x;
    const int nt = blockIdx.x * 128;
    const int mt = blockIdx.y * 128;
    const int zz = blockIdx.z;
    const int z  = zoff + zz;
    const int b  = z >> 1, h = z & 1;
    const float* Aq = qkv + (size_t)b*SS*E3 + h*HDD;        // Q, row stride E3
    const float* Bk = qkv + (size_t)b*SS*E3 + EE + h*HDD;   // K, row stride E3
    float* Cs = scores + (size_t)zz*SS*SS;

    const int tr = t >> 4, tc = t & 15;
    const int lr = t >> 2, lk = (t & 3) * 4;

    float acc[8][8];
#pragma unroll
    for (int i = 0; i < 8; ++i)
#pragma unroll
        for (int j = 0; j < 8; ++j) acc[i][j] = 0.f;

    for (int k0 = 0; k0 < HDD; k0 += 16) {
        float4 a0 = *(const float4*)(Aq + (size_t)(mt + lr)      * E3 + k0 + lk);
        float4 a1 = *(const float4*)(Aq + (size_t)(mt + lr + 64) * E3 + k0 + lk);
        float4 b0 = *(const float4*)(Bk + (size_t)(nt + lr)      * E3 + k0 + lk);
        float4 b1 = *(const float4*)(Bk + (size_t)(nt + lr + 64) * E3 + k0 + lk);
        __syncthreads();
        As[lk+0][lr]    = a0.x; As[lk+1][lr]    = a0.y; As[lk+2][lr]    = a0.z; As[lk+3][lr]    = a0.w;
        As[lk+0][lr+64] = a1.x; As[lk+1][lr+64] = a1.y; As[lk+2][lr+64] = a1.z; As[lk+3][lr+64] = a1.w;
        Bs[lk+0][lr]    = b0.x; Bs[lk+1][lr]    = b0.y; Bs[lk+2][lr]    = b0.z; Bs[lk+3][lr]    = b0.w;
        Bs[lk+0][lr+64] = b1.x; Bs[lk+1][lr+64] = b1.y; Bs[lk+2][lr+64] = b1.z; Bs[lk+3][lr+64] = b1.w;
        __syncthreads();
#pragma unroll
        for (int kk = 0; kk < 16; ++kk) {
            float4 aA = *(const float4*)&As[kk][tr*4];
            float4 aB = *(const float4*)&As[kk][64 + tr*4];
            float4 bA = *(const float4*)&Bs[kk][tc*4];
            float4 bB = *(const float4*)&Bs[kk][64 + tc*4];
            float av[8] = {aA.x,aA.y,aA.z,aA.w,aB.x,aB.y,aB.z,aB.w};
            float bv[8] = {bA.x,bA.y,bA.z,bA.w,bB.x,bB.y,bB.z,bB.w};
#pragma unroll
            for (int i = 0; i < 8; ++i)
#pragma unroll
                for (int j = 0; j < 8; ++j)
                    acc[i][j] = fmaf(av[i], bv[j], acc[i][j]);
        }
    }
#pragma unroll
    for (int i = 0; i < 8; ++i) {
        const int row = mt + ((i < 4) ? (tr*4 + i) : (64 + tr*4 + (i - 4)));
#pragma unroll
        for (int jh = 0; jh < 2; ++jh) {
            const int col = nt + jh*64 + tc*4;
            float4 v = {acc[i][jh*4+0], acc[i][jh*4+1], acc[i][jh*4+2], acc[i][jh*4+3]};
            *(float4*)(Cs + (size_t)row * SS + col) = v;
        }
    }
}

// =====================================================================
// Row softmax over scores (in place, fully normalized).
// =====================================================================
__global__ __launch_bounds__(256) void softmax_rows(float* __restrict__ scores)
{
    const int w    = threadIdx.x >> 6;
    const int lane = threadIdx.x & 63;
    const size_t row = (size_t)blockIdx.x * 4 + w;
    float* p = scores + row * SS + lane * 8;
    float4 v0 = *(float4*)(p);
    float4 v1 = *(float4*)(p + 4);
    const float scale = 0.0625f;
    float m = fmaxf(fmaxf(fmaxf(v0.x, v0.y), fmaxf(v0.z, v0.w)),
                    fmaxf(fmaxf(v1.x, v1.y), fmaxf(v1.z, v1.w)));
#pragma unroll
    for (int off = 32; off >= 1; off >>= 1) m = fmaxf(m, __shfl_xor(m, off));
    v0.x = __expf((v0.x - m) * scale); v0.y = __expf((v0.y - m) * scale);
    v0.z = __expf((v0.z - m) * scale); v0.w = __expf((v0.w - m) * scale);
    v1.x = __expf((v1.x - m) * scale); v1.y = __expf((v1.y - m) * scale);
    v1.z = __expf((v1.z - m) * scale); v1.w = __expf((v1.w - m) * scale);
    float sum = v0.x + v0.y + v0.z + v0.w + v1.x + v1.y + v1.z + v1.w;
#pragma unroll
    for (int off = 32; off >= 1; off >>= 1) sum += __shfl_xor(sum, off);
    float inv = 1.f / sum;
    v0.x *= inv; v0.y *= inv; v0.z *= inv; v0.w *= inv;
    v1.x *= inv; v1.y *= inv; v1.z *= inv; v1.w *= inv;
    *(float4*)(p)     = v0;
    *(float4*)(p + 4) = v1;
}

// =====================================================================
// PV batched GEMM: attn[b, m, h*256 + n] = sum_k P[zz][m][k] V[b,k,h][n]
// =====================================================================
__global__ __launch_bounds__(256) void pv_gemm(
    const float* __restrict__ scores, const float* __restrict__ qkv,
    float* __restrict__ attn, int zoff)
{
    __shared__ __align__(16) float As[16][132];
    __shared__ __align__(16) float Bs[16][132];
    const int t  = threadIdx.x;
    const int nt = blockIdx.x * 128;     // 0 or 128 within head dim
    const int mt = blockIdx.y * 128;
    const int zz = blockIdx.z;
    const int z  = zoff + zz;
    const int b  = z >> 1, h = z & 1;
    const float* P = scores + (size_t)zz*SS*SS;               // row stride SS
    const float* V = qkv + (size_t)b*SS*E3 + 2*EE + h*HDD;    // row k stride E3
    float* C = attn + (size_t)b*SS*EE + h*HDD;                // row stride EE

    const int tr = t >> 4, tc = t & 15;
    const int lr = t >> 2, lk = (t & 3) * 4;
    const int bk   = t >> 5;            // 0..7
    const int bcol = (t & 31) * 4;      // 0..124

    float acc[8][8];
#pragma unroll
    for (int i = 0; i < 8; ++i)
#pragma unroll
        for (int j = 0; j < 8; ++j) acc[i][j] = 0.f;

    for (int k0 = 0; k0 < SS; k0 += 16) {
        float4 a0 = *(const float4*)(P + (size_t)(mt + lr)      * SS + k0 + lk);
        float4 a1 = *(const float4*)(P + (size_t)(mt + lr + 64) * SS + k0 + lk);
        float4 v0 = *(const float4*)(V + (size_t)(k0 + bk)     * E3 + nt + bcol);
        float4 v1 = *(const float4*)(V + (size_t)(k0 + bk + 8) * E3 + nt + bcol);
        __syncthreads();
        As[lk+0][lr]    = a0.x; As[lk+1][lr]    = a0.y; As[lk+2][lr]    = a0.z; As[lk+3][lr]    = a0.w;
        As[lk+0][lr+64] = a1.x; As[lk+1][lr+64] = a1.y; As[lk+2][lr+64] = a1.z; As[lk+3][lr+64] = a1.w;
        *(float4*)&Bs[bk][bcol]   = v0;
        *(float4*)&Bs[bk+8][bcol] = v1;
        __syncthreads();
#pragma unroll
        for (int kk = 0; kk < 16; ++kk) {
            float4 aA = *(const float4*)&As[kk][tr*4];
            float4 aB = *(const float4*)&As[kk][64 + tr*4];
            float4 bA = *(const float4*)&Bs[kk][tc*4];
            float4 bB = *(const float4*)&Bs[kk][64 + tc*4];
            float av[8] = {aA.x,aA.y,aA.z,aA.w,aB.x,aB.y,aB.z,aB.w};
            float bv[8] = {bA.x,bA.y,bA.z,bA.w,bB.x,bB.y,bB.z,bB.w};
#pragma unroll
            for (int i = 0; i < 8; ++i)
#pragma unroll
                for (int j = 0; j < 8; ++j)
                    acc[i][j] = fmaf(av[i], bv[j], acc[i][j]);
        }
    }
#pragma unroll
    for (int i = 0; i < 8; ++i) {
        const int row = mt + ((i < 4) ? (tr*4 + i) : (64 + tr*4 + (i - 4)));
#pragma unroll
        for (int jh = 0; jh < 2; ++jh) {
            const int col = nt + jh*64 + tc*4;
            float4 v = {acc[i][jh*4+0], acc[i][jh*4+1], acc[i][jh*4+2], acc[i][jh*4+3]};
            *(float4*)(C + (size_t)row * EE + col) = v;
        }
    }
}

// =====================================================================
// CRF emissions: fc[row][j] = dot(dec[row], crf_w[j]) + crf_b[j]
// =====================================================================
__global__ __launch_bounds__(192) void fc_crf_kernel(
    const float* __restrict__ dec, const float* __restrict__ W,
    const float* __restrict__ bias, float* __restrict__ out)
{
    __shared__ __align__(16) float Ws[NT][516];
    for (int i = threadIdx.x; i < NT*128; i += 192) {
        int j = i >> 7, c = (i & 127) * 4;
        *(float4*)&Ws[j][c] = *(const float4*)(W + (size_t)j*EE + c);
    }
    __syncthreads();
    const int t = threadIdx.x;
    const int rloc = t / NT;
    const int j = t - rloc * NT;
    const int row = blockIdx.x * 8 + rloc;
    const float4* a = (const float4*)(dec + (size_t)row * EE);
    float acc = 0.f;
#pragma unroll 4
    for (int i = 0; i < 128; ++i) {
        float4 x = a[i];
        float4 y = *(const float4*)&Ws[j][i*4];
        acc += x.x*y.x + x.y*y.y + x.z*y.z + x.w*y.w;
    }
    out[(size_t)row * NT + j] = acc + bias[j];
}

// =====================================================================
// Merged CRF + seg. CRF recursion register/shuffle-based (round-4 form).
// =====================================================================
__global__ __launch_bounds__(256) void crf_seg_kernel(
    const float* __restrict__ fc, const int* __restrict__ labels,
    const float* __restrict__ start_t, const float* __restrict__ end_t,
    const float* __restrict__ trans, const float* __restrict__ dec,
    const float* __restrict__ ent_w, const float* __restrict__ ent_b,
    float* __restrict__ num, float* __restrict__ den,
    float* __restrict__ crf_out, float* __restrict__ segout)
{
    __shared__ unsigned char hist[4][(SS-1)*NT];

    const int blk = blockIdx.x;
    if (blk >= 24) {
        // ---------------- segmentation head: 4 rows per block -----------
        const int w    = threadIdx.x >> 6;
        const int lane = threadIdx.x & 63;
        const int row  = (blk - 24) * 4 + w;          // 0 .. MR-1
        const float4* a  = (const float4*)(dec + (size_t)row * EE);
        const float4* w0 = (const float4*)(ent_w);
        const float4* w1 = (const float4*)(ent_w + EE);
        float acc0 = 0.f, acc1 = 0.f;
#pragma unroll
        for (int i = 0; i < 2; ++i) {
            int idx = lane * 2 + i;
            float4 x = a[idx];
            float4 u = w0[idx];
            float4 v = w1[idx];
            acc0 += x.x*u.x + x.y*u.y + x.z*u.z + x.w*u.w;
            acc1 += x.x*v.x + x.y*v.y + x.z*v.z + x.w*v.w;
        }
#pragma unroll
        for (int off = 32; off >= 1; off >>= 1) {
            acc0 += __shfl_xor(acc0, off);
            acc1 += __shfl_xor(acc1, off);
        }
        if (lane == 0) {
            float l0 = acc0 + ent_b[0];
            float l1 = acc1 + ent_b[1];
            float m  = fmaxf(l0, l1);
            float lse = m + __logf(__expf(l0 - m) + __expf(l1 - m));
            segout[(size_t)row*2 + 0] = l0 - lse;
            segout[(size_t)row*2 + 1] = l1 - lse;
        }
        return;
    }

    // ---------------- CRF: 24 blocks x 4 waves = 96 single-wave tasks ----
    const int w    = threadIdx.x >> 6;
    const int lane = threadIdx.x & 63;
    const int task = blk * 4 + w;       // 0..95
    const int role = task >> 5;         // 0=forward, 1=viterbi, 2=numerator
    const int b    = task & 31;
    const float* fcb = fc + (size_t)b * SS * NT;

    if (role == 2) {
        // ---- numerator ----
        float acc = 0.f;
        for (int s = 1 + lane; s < SS; s += 64) {
            int prev = labels[b*SS + s - 1];
            int cur  = labels[b*SS + s];
            acc += trans[prev*NT + cur] + fcb[(size_t)s*NT + cur];
        }
        if (lane == 0) {
            int l0 = labels[b*SS];
            acc += start_t[l0] + fcb[l0] + end_t[labels[b*SS + SS - 1]];
        }
#pragma unroll
        for (int off = 32; off >= 1; off >>= 1) acc += __shfl_xor(acc, off);
        if (lane == 0) num[b] = acc;
        return;
    }

    // lane j owns destination tag j; trC[i] = trans[i][j] (source i -> j)
    const int j = (lane < NT) ? lane : 0;
    float trC[NT];
#pragma unroll
    for (int i = 0; i < NT; ++i) trC[i] = trans[i*NT + j];
    float sc = start_t[j] + fcb[j];

    if (role == 0) {
        // ---- forward (log-normalizer) ----
        float em_next = fcb[NT + j];
        for (int s = 1; s < SS; ++s) {
            float em = em_next;
            int snx = (s + 1 < SS) ? s + 1 : s;
            em_next = fcb[(size_t)snx * NT + j];     // prefetch next step
            float tv[NT];
#pragma unroll
            for (int i = 0; i < NT; ++i) tv[i] = __shfl(sc, i) + trC[i];
            float mx[NT];
#pragma unroll
            for (int i = 0; i < NT; ++i) mx[i] = tv[i];
#pragma unroll
            for (int st = 1; st < NT; st <<= 1)
#pragma unroll
                for (int i = 0; i + st < NT; i += 2*st)
                    mx[i] = fmaxf(mx[i], mx[i+st]);
            const float m = mx[0];
            float ev[NT];
#pragma unroll
            for (int i = 0; i < NT; ++i) ev[i] = __expf(tv[i] - m);
#pragma unroll
            for (int st = 1; st < NT; st <<= 1)
#pragma unroll
                for (int i = 0; i + st < NT; i += 2*st)
                    ev[i] += ev[i+st];
            sc = m + __logf(ev[0]) + em;
        }
        float v = (lane < NT) ? sc + end_t[j] : -1e30f;
        float m2 = v;
#pragma unroll
        for (int off = 32; off >= 1; off >>= 1) m2 = fmaxf(m2, __shfl_xor(m2, off));
        float e = (lane < NT) ? __expf(v - m2) : 0.f;
#pragma unroll
        for (int off = 32; off >= 1; off >>= 1) e += __shfl_xor(e, off);
        if (lane == 0) den[b] = m2 + __logf(e);
    } else {
        // ---- viterbi ----
        volatile unsigned char* hw = hist[w];
        float em_next = fcb[NT + j];
        for (int s = 1; s < SS; ++s) {
            float em = em_next;
            int snx = (s + 1 < SS) ? s + 1 : s;
            em_next = fcb[(size_t)snx * NT + j];
            float tv[NT]; int ti[NT];
#pragma unroll
            for (int i = 0; i < NT; ++i) { tv[i] = __shfl(sc, i) + trC[i]; ti[i] = i; }
            // first-tie argmax tree: lower index wins on equality
#pragma unroll
            for (int st = 1; st < NT; st <<= 1)
#pragma unroll
                for (int i = 0; i + st < NT; i += 2*st)
                    if (tv[i+st] > tv[i]) { tv[i] = tv[i+st]; ti[i] = ti[i+st]; }
            sc = tv[0] + em;
            if (lane < NT) hw[(s-1)*NT + lane] = (unsigned char)ti[0];
        }
        // final argmax over lanes (first-tie, lowest lane wins)
        float bv = (lane < NT) ? sc + end_t[j] : -1e30f;
        int bi = (lane < NT) ? lane : NT;
#pragma unroll
        for (int off = 32; off >= 1; off >>= 1) {
            float ov = __shfl_xor(bv, off);
            int   oi = __shfl_xor(bi, off);
            if (ov > bv || (ov == bv && oi < bi)) { bv = ov; bi = oi; }
        }
        WAVE_BAR();
        if (lane == 0) {
            int tag = bi;
            crf_out[(size_t)b*SS + SS - 1] = (float)tag;
            for (int s = SS - 2; s >= 0; --s) {
                tag = hw[s*NT + tag];
                crf_out[(size_t)b*SS + s] = (float)tag;
            }
        }
    }
}

// =====================================================================
// Final scalar: -llh = -( sum_b(num[b]-den[b]) / 16384 )
// =====================================================================
__global__ __launch_bounds__(64) void llh_kernel(
    const float* __restrict__ num, const float* __restrict__ den,
    float* __restrict__ out)
{
    int t = threadIdx.x;
    float v = (t < BB) ? (num[t] - den[t]) : 0.f;
#pragma unroll
    for (int off = 32; off >= 1; off >>= 1) v += __shfl_xor(v, off);
    if (t == 0) out[(size_t)MR * 3] = -(v / (float)MR);
}

extern "C" void kernel_launch(void* const* d_in, const int* in_sizes, int n_in,
                              void* d_out, int out_size, void* d_ws, size_t ws_size,
                              hipStream_t stream) {
    const float* enc     = (const float*)d_in[0];
    const int*   labels  = (const int*)  d_in[1];
    // d_in[2] = mask (all ones by construction; unused)
    const float* Win     = (const float*)d_in[3];
    const float* bin     = (const float*)d_in[4];
    const float* Wout    = (const float*)d_in[5];
    const float* bout    = (const float*)d_in[6];
    const float* crf_w   = (const float*)d_in[7];
    const float* crf_b   = (const float*)d_in[8];
    const float* start_t = (const float*)d_in[9];
    const float* end_t   = (const float*)d_in[10];
    const float* trans   = (const float*)d_in[11];
    const float* ent_w   = (const float*)d_in[12];
    const float* ent_b   = (const float*)d_in[13];
    float* out = (float*)d_out;

    // Workspace layout — scores half (33.5 MB) aliases dec; scores are
    // dead before dec is written.
    float* ws   = (float*)d_ws;
    float* qkv  = ws;                                 // 16384*1536
    float* attn = qkv  + (size_t)MR * E3;             // 16384*512
    float* big  = attn + (size_t)MR * EE;             // 8,388,608 floats
    float* sch  = big;                                // scores half: 32*512*512
    float* dec  = big;                                // dec aliases scores
    float* fc   = big  + (size_t)MR * EE;             // 16384*24
    float* num  = fc   + (size_t)MR * NT;             // 32
    float* den  = num  + BB;                          // 32

    dim3 blk(256);
    // 1. qkv = enc @ Win^T + bin
    gemm_bt128<<<dim3(E3/128, MR/128), blk, 0, stream>>>(enc, Win, bin, qkv, MR, E3, EE, 0);
    // 2. attention in two z-passes of 32 (b,h) pairs each
    for (int p = 0; p < 2; ++p) {
        int zoff = p * 32;
        qk_gemm<<<dim3(SS/128, SS/128, 32), blk, 0, stream>>>(qkv, sch, zoff);
        softmax_rows<<<(32*SS)/4, blk, 0, stream>>>(sch);
        pv_gemm<<<dim3(HDD/128, SS/128, 32), blk, 0, stream>>>(sch, qkv, attn, zoff);
    }
    // 3. dec = relu(attn @ Wout^T + bout)   (overwrites scores region)
    gemm_bt128<<<dim3(EE/128, MR/128), blk, 0, stream>>>(attn, Wout, bout, dec, MR, EE, EE, 1);
    // 4. fc emissions
    fc_crf_kernel<<<MR/8, dim3(192), 0, stream>>>(dec, crf_w, crf_b, fc);
    // 5. CRF (forward+viterbi+numerator) + seg head merged
    crf_seg_kernel<<<24 + MR/4, blk, 0, stream>>>(
        fc, labels, start_t, end_t, trans, dec, ent_w, ent_b,
        num, den, out, out + MR);
    // 6. -llh scalar -> d_out[49152]
    llh_kernel<<<1, 64, 0, stream>>>(num, den, out);
}

// Round 6
// 653.709 us; speedup vs baseline: 2.4994x; 1.6070x over previous
//
#include <hip/hip_runtime.h>

#define BB 32
#define SS 512
#define EE 512
#define NHH 2
#define HDD 256
#define E3 1536
#define NT 24
#define MR (BB*SS)   // 16384

#define WAVE_BAR() __builtin_amdgcn_wave_barrier()

typedef _Float16 half8  __attribute__((ext_vector_type(8)));
typedef _Float16 half4v __attribute__((ext_vector_type(4)));
typedef float    f32x4  __attribute__((ext_vector_type(4)));

// =====================================================================
// fp32-accurate GEMM via fp16 3-product MFMA split (Ootomo):
//   C = A(M x K) . B^T + bias, A/B fp32 in HBM, split to hi/lo fp16 in
//   LDS during staging (RNE: rep error ~2^-23 — below fp32 reorder noise).
// 128x128 block tile, 256 thr = 2x2 waves, per wave 4x4 tiles of
// mfma_f32_16x16x32_f16, 3 mfma per tile pair (hh, lh, hl).
// LDS tiles in fragment-native layout: [tile(16 rows)][row][k] with row
// stride 40 f16 (80 B) -> staging writes conflict-free, fragment
// ds_read_b128 = 1KB near-contiguous per wave, 16B aligned.
// z-batch indexing: zg = zOff + blockIdx.z; off = (zg>>1)*sHi + (zg&1)*sLo.
// BN=0: B is row-major N x K (B^T form). BN=1: B is row-major K x N (V).
// =====================================================================
template<int BN>
__global__ __launch_bounds__(256) void mfma_gemm(
    const float* __restrict__ A, int lda, long sAhi, long sAlo, int zA,
    const float* __restrict__ B, int ldb, long sBhi, long sBlo, int zB,
    const float* __restrict__ bias,
    float* __restrict__ C, int ldc, long sChi, long sClo, int zC,
    int K, int relu)
{
    __shared__ __align__(16) _Float16 sAh[8*640];
    __shared__ __align__(16) _Float16 sAl[8*640];
    __shared__ __align__(16) _Float16 sBh[8*640];
    __shared__ __align__(16) _Float16 sBl[8*640];

    const int t = threadIdx.x;
    const int z = blockIdx.z;
    const int za = zA + z, zb = zB + z, zc = zC + z;
    const float* Ab = A + (size_t)(za>>1)*sAhi + (size_t)(za&1)*sAlo
                        + (size_t)blockIdx.y*128*lda;
    const float* Bb = B + (size_t)(zb>>1)*sBhi + (size_t)(zb&1)*sBlo
                        + (BN ? (size_t)blockIdx.x*128
                              : (size_t)blockIdx.x*128*ldb);

    const int wv = t >> 6, lane = t & 63;
    const int wm = wv >> 1, wn = wv & 1;
    const int lm = lane & 15, lq = lane >> 4;

    f32x4 acc[4][4];
#pragma unroll
    for (int i = 0; i < 4; ++i)
#pragma unroll
        for (int j = 0; j < 4; ++j) acc[i][j] = (f32x4){0.f,0.f,0.f,0.f};

    const int r8  = t >> 3;         // 0..31 (staging row base)
    const int kc  = (t & 7) * 4;    // 0..28 (staging k chunk)
    const int bnk = (t >> 7) * 16;  // BN staging: k half
    const int bnn = t & 127;        // BN staging: n

    for (int k0 = 0; k0 < K; k0 += 32) {
        float4 ga[4], gb[4]; float gv[16];
#pragma unroll
        for (int i = 0; i < 4; ++i)
            ga[i] = *(const float4*)(Ab + (size_t)(r8 + 32*i)*lda + k0 + kc);
        if (BN) {
#pragma unroll
            for (int i = 0; i < 16; ++i)
                gv[i] = Bb[(size_t)(k0 + bnk + i)*ldb + bnn];
        } else {
#pragma unroll
            for (int i = 0; i < 4; ++i)
                gb[i] = *(const float4*)(Bb + (size_t)(r8 + 32*i)*ldb + k0 + kc);
        }
        __syncthreads();   // previous iteration's fragment reads complete
#pragma unroll
        for (int i = 0; i < 4; ++i) {
            const int row  = r8 + 32*i;
            const int base = (row >> 4)*640 + (row & 15)*40 + kc;
            float4 a = ga[i];
            _Float16 h0 = (_Float16)a.x, h1 = (_Float16)a.y,
                     h2 = (_Float16)a.z, h3 = (_Float16)a.w;
            _Float16 l0 = (_Float16)(a.x - (float)h0),
                     l1 = (_Float16)(a.y - (float)h1),
                     l2 = (_Float16)(a.z - (float)h2),
                     l3 = (_Float16)(a.w - (float)h3);
            *(half4v*)&sAh[base] = (half4v){h0,h1,h2,h3};
            *(half4v*)&sAl[base] = (half4v){l0,l1,l2,l3};
        }
        if (BN) {
#pragma unroll
            for (int i = 0; i < 16; ++i) {
                const int k = bnk + i;
                float v = gv[i];
                _Float16 h = (_Float16)v;
                _Float16 l = (_Float16)(v - (float)h);
                const int base = (bnn >> 4)*640 + (bnn & 15)*40 + k;
                sBh[base] = h;
                sBl[base] = l;
            }
        } else {
#pragma unroll
            for (int i = 0; i < 4; ++i) {
                const int row  = r8 + 32*i;
                const int base = (row >> 4)*640 + (row & 15)*40 + kc;
                float4 b = gb[i];
                _Float16 h0 = (_Float16)b.x, h1 = (_Float16)b.y,
                         h2 = (_Float16)b.z, h3 = (_Float16)b.w;
                _Float16 l0 = (_Float16)(b.x - (float)h0),
                         l1 = (_Float16)(b.y - (float)h1),
                         l2 = (_Float16)(b.z - (float)h2),
                         l3 = (_Float16)(b.w - (float)h3);
                *(half4v*)&sBh[base] = (half4v){h0,h1,h2,h3};
                *(half4v*)&sBl[base] = (half4v){l0,l1,l2,l3};
            }
        }
        __syncthreads();

        half8 bhf[4], blf[4];
#pragma unroll
        for (int j = 0; j < 4; ++j) {
            const int tb = (wn*4 + j)*640 + lm*40 + lq*8;
            bhf[j] = *(const half8*)&sBh[tb];
            blf[j] = *(const half8*)&sBl[tb];
        }
#pragma unroll
        for (int i = 0; i < 4; ++i) {
            const int ta = (wm*4 + i)*640 + lm*40 + lq*8;
            half8 ah = *(const half8*)&sAh[ta];
            half8 al = *(const half8*)&sAl[ta];
#pragma unroll
            for (int j = 0; j < 4; ++j) {
                acc[i][j] = __builtin_amdgcn_mfma_f32_16x16x32_f16(ah, bhf[j], acc[i][j], 0, 0, 0);
                acc[i][j] = __builtin_amdgcn_mfma_f32_16x16x32_f16(al, bhf[j], acc[i][j], 0, 0, 0);
                acc[i][j] = __builtin_amdgcn_mfma_f32_16x16x32_f16(ah, blf[j], acc[i][j], 0, 0, 0);
            }
        }
    }

    // epilogue: C/D layout col = lane&15, row = quad*4 + reg
    float* Cb = C + (size_t)(zc>>1)*sChi + (size_t)(zc&1)*sClo;
#pragma unroll
    for (int j = 0; j < 4; ++j) {
        const int col = blockIdx.x*128 + (wn*4 + j)*16 + lm;
        const float bj = bias ? bias[col] : 0.f;
#pragma unroll
        for (int i = 0; i < 4; ++i) {
            const int row0 = blockIdx.y*128 + (wm*4 + i)*16 + lq*4;
#pragma unroll
            for (int r = 0; r < 4; ++r) {
                float v = acc[i][j][r] + bj;
                if (relu) v = fmaxf(v, 0.f);
                Cb[(size_t)(row0 + r)*ldc + col] = v;
            }
        }
    }
}

// =====================================================================
// Row softmax over scores (in place, fully normalized).
// =====================================================================
__global__ __launch_bounds__(256) void softmax_rows(float* __restrict__ scores)
{
    const int w    = threadIdx.x >> 6;
    const int lane = threadIdx.x & 63;
    const size_t row = (size_t)blockIdx.x * 4 + w;
    float* p = scores + row * SS + lane * 8;
    float4 v0 = *(float4*)(p);
    float4 v1 = *(float4*)(p + 4);
    const float scale = 0.0625f;
    float m = fmaxf(fmaxf(fmaxf(v0.x, v0.y), fmaxf(v0.z, v0.w)),
                    fmaxf(fmaxf(v1.x, v1.y), fmaxf(v1.z, v1.w)));
#pragma unroll
    for (int off = 32; off >= 1; off >>= 1) m = fmaxf(m, __shfl_xor(m, off));
    v0.x = __expf((v0.x - m) * scale); v0.y = __expf((v0.y - m) * scale);
    v0.z = __expf((v0.z - m) * scale); v0.w = __expf((v0.w - m) * scale);
    v1.x = __expf((v1.x - m) * scale); v1.y = __expf((v1.y - m) * scale);
    v1.z = __expf((v1.z - m) * scale); v1.w = __expf((v1.w - m) * scale);
    float sum = v0.x + v0.y + v0.z + v0.w + v1.x + v1.y + v1.z + v1.w;
#pragma unroll
    for (int off = 32; off >= 1; off >>= 1) sum += __shfl_xor(sum, off);
    float inv = 1.f / sum;
    v0.x *= inv; v0.y *= inv; v0.z *= inv; v0.w *= inv;
    v1.x *= inv; v1.y *= inv; v1.z *= inv; v1.w *= inv;
    *(float4*)(p)     = v0;
    *(float4*)(p + 4) = v1;
}

// =====================================================================
// CRF emissions: fc[row][j] = dot(dec[row], crf_w[j]) + crf_b[j]
// =====================================================================
__global__ __launch_bounds__(192) void fc_crf_kernel(
    const float* __restrict__ dec, const float* __restrict__ W,
    const float* __restrict__ bias, float* __restrict__ out)
{
    __shared__ __align__(16) float Ws[NT][516];
    for (int i = threadIdx.x; i < NT*128; i += 192) {
        int j = i >> 7, c = (i & 127) * 4;
        *(float4*)&Ws[j][c] = *(const float4*)(W + (size_t)j*EE + c);
    }
    __syncthreads();
    const int t = threadIdx.x;
    const int rloc = t / NT;
    const int j = t - rloc * NT;
    const int row = blockIdx.x * 8 + rloc;
    const float4* a = (const float4*)(dec + (size_t)row * EE);
    float acc = 0.f;
#pragma unroll 4
    for (int i = 0; i < 128; ++i) {
        float4 x = a[i];
        float4 y = *(const float4*)&Ws[j][i*4];
        acc += x.x*y.x + x.y*y.y + x.z*y.z + x.w*y.w;
    }
    out[(size_t)row * NT + j] = acc + bias[j];
}

// =====================================================================
// Merged CRF + seg. CRF recursion register/shuffle-based (round-4 form).
// =====================================================================
__global__ __launch_bounds__(256) void crf_seg_kernel(
    const float* __restrict__ fc, const int* __restrict__ labels,
    const float* __restrict__ start_t, const float* __restrict__ end_t,
    const float* __restrict__ trans, const float* __restrict__ dec,
    const float* __restrict__ ent_w, const float* __restrict__ ent_b,
    float* __restrict__ num, float* __restrict__ den,
    float* __restrict__ crf_out, float* __restrict__ segout)
{
    __shared__ unsigned char hist[4][(SS-1)*NT];

    const int blk = blockIdx.x;
    if (blk >= 24) {
        // ---------------- segmentation head: 4 rows per block -----------
        const int w    = threadIdx.x >> 6;
        const int lane = threadIdx.x & 63;
        const int row  = (blk - 24) * 4 + w;          // 0 .. MR-1
        const float4* a  = (const float4*)(dec + (size_t)row * EE);
        const float4* w0 = (const float4*)(ent_w);
        const float4* w1 = (const float4*)(ent_w + EE);
        float acc0 = 0.f, acc1 = 0.f;
#pragma unroll
        for (int i = 0; i < 2; ++i) {
            int idx = lane * 2 + i;
            float4 x = a[idx];
            float4 u = w0[idx];
            float4 v = w1[idx];
            acc0 += x.x*u.x + x.y*u.y + x.z*u.z + x.w*u.w;
            acc1 += x.x*v.x + x.y*v.y + x.z*v.z + x.w*v.w;
        }
#pragma unroll
        for (int off = 32; off >= 1; off >>= 1) {
            acc0 += __shfl_xor(acc0, off);
            acc1 += __shfl_xor(acc1, off);
        }
        if (lane == 0) {
            float l0 = acc0 + ent_b[0];
            float l1 = acc1 + ent_b[1];
            float m  = fmaxf(l0, l1);
            float lse = m + __logf(__expf(l0 - m) + __expf(l1 - m));
            segout[(size_t)row*2 + 0] = l0 - lse;
            segout[(size_t)row*2 + 1] = l1 - lse;
        }
        return;
    }

    // ---------------- CRF: 24 blocks x 4 waves = 96 single-wave tasks ----
    const int w    = threadIdx.x >> 6;
    const int lane = threadIdx.x & 63;
    const int task = blk * 4 + w;       // 0..95
    const int role = task >> 5;         // 0=forward, 1=viterbi, 2=numerator
    const int b    = task & 31;
    const float* fcb = fc + (size_t)b * SS * NT;

    if (role == 2) {
        // ---- numerator ----
        float acc = 0.f;
        for (int s = 1 + lane; s < SS; s += 64) {
            int prev = labels[b*SS + s - 1];
            int cur  = labels[b*SS + s];
            acc += trans[prev*NT + cur] + fcb[(size_t)s*NT + cur];
        }
        if (lane == 0) {
            int l0 = labels[b*SS];
            acc += start_t[l0] + fcb[l0] + end_t[labels[b*SS + SS - 1]];
        }
#pragma unroll
        for (int off = 32; off >= 1; off >>= 1) acc += __shfl_xor(acc, off);
        if (lane == 0) num[b] = acc;
        return;
    }

    // lane j owns destination tag j; trC[i] = trans[i][j] (source i -> j)
    const int j = (lane < NT) ? lane : 0;
    float trC[NT];
#pragma unroll
    for (int i = 0; i < NT; ++i) trC[i] = trans[i*NT + j];
    float sc = start_t[j] + fcb[j];

    if (role == 0) {
        // ---- forward (log-normalizer) ----
        float em_next = fcb[NT + j];
        for (int s = 1; s < SS; ++s) {
            float em = em_next;
            int snx = (s + 1 < SS) ? s + 1 : s;
            em_next = fcb[(size_t)snx * NT + j];     // prefetch next step
            float tv[NT];
#pragma unroll
            for (int i = 0; i < NT; ++i) tv[i] = __shfl(sc, i) + trC[i];
            float mx[NT];
#pragma unroll
            for (int i = 0; i < NT; ++i) mx[i] = tv[i];
#pragma unroll
            for (int st = 1; st < NT; st <<= 1)
#pragma unroll
                for (int i = 0; i + st < NT; i += 2*st)
                    mx[i] = fmaxf(mx[i], mx[i+st]);
            const float m = mx[0];
            float ev[NT];
#pragma unroll
            for (int i = 0; i < NT; ++i) ev[i] = __expf(tv[i] - m);
#pragma unroll
            for (int st = 1; st < NT; st <<= 1)
#pragma unroll
                for (int i = 0; i + st < NT; i += 2*st)
                    ev[i] += ev[i+st];
            sc = m + __logf(ev[0]) + em;
        }
        float v = (lane < NT) ? sc + end_t[j] : -1e30f;
        float m2 = v;
#pragma unroll
        for (int off = 32; off >= 1; off >>= 1) m2 = fmaxf(m2, __shfl_xor(m2, off));
        float e = (lane < NT) ? __expf(v - m2) : 0.f;
#pragma unroll
        for (int off = 32; off >= 1; off >>= 1) e += __shfl_xor(e, off);
        if (lane == 0) den[b] = m2 + __logf(e);
    } else {
        // ---- viterbi ----
        volatile unsigned char* hw = hist[w];
        float em_next = fcb[NT + j];
        for (int s = 1; s < SS; ++s) {
            float em = em_next;
            int snx = (s + 1 < SS) ? s + 1 : s;
            em_next = fcb[(size_t)snx * NT + j];
            float tv[NT]; int ti[NT];
#pragma unroll
            for (int i = 0; i < NT; ++i) { tv[i] = __shfl(sc, i) + trC[i]; ti[i] = i; }
            // first-tie argmax tree: lower index wins on equality
#pragma unroll
            for (int st = 1; st < NT; st <<= 1)
#pragma unroll
                for (int i = 0; i + st < NT; i += 2*st)
                    if (tv[i+st] > tv[i]) { tv[i] = tv[i+st]; ti[i] = ti[i+st]; }
            sc = tv[0] + em;
            if (lane < NT) hw[(s-1)*NT + lane] = (unsigned char)ti[0];
        }
        // final argmax over lanes (first-tie, lowest lane wins)
        float bv = (lane < NT) ? sc + end_t[j] : -1e30f;
        int bi = (lane < NT) ? lane : NT;
#pragma unroll
        for (int off = 32; off >= 1; off >>= 1) {
            float ov = __shfl_xor(bv, off);
            int   oi = __shfl_xor(bi, off);
            if (ov > bv || (ov == bv && oi < bi)) { bv = ov; bi = oi; }
        }
        WAVE_BAR();
        if (lane == 0) {
            int tag = bi;
            crf_out[(size_t)b*SS + SS - 1] = (float)tag;
            for (int s = SS - 2; s >= 0; --s) {
                tag = hw[s*NT + tag];
                crf_out[(size_t)b*SS + s] = (float)tag;
            }
        }
    }
}

// =====================================================================
// Final scalar: -llh = -( sum_b(num[b]-den[b]) / 16384 )
// =====================================================================
__global__ __launch_bounds__(64) void llh_kernel(
    const float* __restrict__ num, const float* __restrict__ den,
    float* __restrict__ out)
{
    int t = threadIdx.x;
    float v = (t < BB) ? (num[t] - den[t]) : 0.f;
#pragma unroll
    for (int off = 32; off >= 1; off >>= 1) v += __shfl_xor(v, off);
    if (t == 0) out[(size_t)MR * 3] = -(v / (float)MR);
}

extern "C" void kernel_launch(void* const* d_in, const int* in_sizes, int n_in,
                              void* d_out, int out_size, void* d_ws, size_t ws_size,
                              hipStream_t stream) {
    const float* enc     = (const float*)d_in[0];
    const int*   labels  = (const int*)  d_in[1];
    // d_in[2] = mask (all ones by construction; unused)
    const float* Win     = (const float*)d_in[3];
    const float* bin     = (const float*)d_in[4];
    const float* Wout    = (const float*)d_in[5];
    const float* bout    = (const float*)d_in[6];
    const float* crf_w   = (const float*)d_in[7];
    const float* crf_b   = (const float*)d_in[8];
    const float* start_t = (const float*)d_in[9];
    const float* end_t   = (const float*)d_in[10];
    const float* trans   = (const float*)d_in[11];
    const float* ent_w   = (const float*)d_in[12];
    const float* ent_b   = (const float*)d_in[13];
    float* out = (float*)d_out;

    // Workspace layout — scores half (33.5 MB) aliases dec; scores are
    // dead before dec is written.
    float* ws   = (float*)d_ws;
    float* qkv  = ws;                                 // 16384*1536
    float* attn = qkv  + (size_t)MR * E3;             // 16384*512
    float* big  = attn + (size_t)MR * EE;             // 8,388,608 floats
    float* sch  = big;                                // scores half: 32*512*512
    float* dec  = big;                                // dec aliases scores
    float* fc   = big  + (size_t)MR * EE;             // 16384*24
    float* num  = fc   + (size_t)MR * NT;             // 32
    float* den  = num  + BB;                          // 32

    dim3 blk(256);
    // 1. qkv = enc @ Win^T + bin
    mfma_gemm<0><<<dim3(E3/128, MR/128, 1), blk, 0, stream>>>(
        enc, EE, 0, 0, 0,  Win, EE, 0, 0, 0,  bin,
        qkv, E3, 0, 0, 0,  EE, 0);
    // 2. attention in two z-passes of 32 (b,h) pairs each
    for (int p = 0; p < 2; ++p) {
        int zoff = p * 32;
        // scores[z][m][n] = Q[m].K[n]
        mfma_gemm<0><<<dim3(SS/128, SS/128, 32), blk, 0, stream>>>(
            qkv,      E3, (long)SS*E3, HDD, zoff,
            qkv + EE, E3, (long)SS*E3, HDD, zoff,
            nullptr,
            sch, SS, 2L*SS*SS, (long)SS*SS, 0,
            HDD, 0);
        softmax_rows<<<(32*SS)/4, blk, 0, stream>>>(sch);
        // attn[b,m,h*256+n] = sum_k P[z][m][k] V[b,k,h][n]
        mfma_gemm<1><<<dim3(HDD/128, SS/128, 32), blk, 0, stream>>>(
            sch, SS, 2L*SS*SS, (long)SS*SS, 0,
            qkv + 2*EE, E3, (long)SS*E3, HDD, zoff,
            nullptr,
            attn, EE, (long)SS*EE, HDD, zoff,
            SS, 0);
    }
    // 3. dec = relu(attn @ Wout^T + bout)   (overwrites scores region)
    mfma_gemm<0><<<dim3(EE/128, MR/128, 1), blk, 0, stream>>>(
        attn, EE, 0, 0, 0,  Wout, EE, 0, 0, 0,  bout,
        dec, EE, 0, 0, 0,  EE, 1);
    // 4. fc emissions
    fc_crf_kernel<<<MR/8, dim3(192), 0, stream>>>(dec, crf_w, crf_b, fc);
    // 5. CRF (forward+viterbi+numerator) + seg head merged
    crf_seg_kernel<<<24 + MR/4, blk, 0, stream>>>(
        fc, labels, start_t, end_t, trans, dec, ent_w, ent_b,
        num, den, out, out + MR);
    // 6. -llh scalar -> d_out[49152]
    llh_kernel<<<1, 64, 0, stream>>>(num, den, out);
}

// Round 7
// 606.396 us; speedup vs baseline: 2.6945x; 1.0780x over previous
//
#include <hip/hip_runtime.h>

#define BB 32
#define SS 512
#define EE 512
#define NHH 2
#define HDD 256
#define E3 1536
#define NT 24
#define MR (BB*SS)   // 16384

#define WAVE_BAR() __builtin_amdgcn_wave_barrier()

typedef _Float16 half8  __attribute__((ext_vector_type(8)));
typedef _Float16 half4v __attribute__((ext_vector_type(4)));
typedef float    f32x4  __attribute__((ext_vector_type(4)));

// =====================================================================
// fp32-accurate GEMM via fp16 3-product MFMA split (Ootomo):
//   C = A(M x K) . B^T + bias, A/B fp32 in HBM, split to hi/lo fp16 in
//   LDS during staging (RNE: rep error ~2^-23 — below fp32 reorder noise).
// 128x128 block tile, 256 thr = 2x2 waves, per wave 4x4 tiles of
// mfma_f32_16x16x32_f16, 3 mfma per tile pair (hh, lh, hl).
// BN=0: B is row-major N x K (B^T form). BN=1: B is row-major K x N (V).
// =====================================================================
template<int BN>
__global__ __launch_bounds__(256) void mfma_gemm(
    const float* __restrict__ A, int lda, long sAhi, long sAlo, int zA,
    const float* __restrict__ B, int ldb, long sBhi, long sBlo, int zB,
    const float* __restrict__ bias,
    float* __restrict__ C, int ldc, long sChi, long sClo, int zC,
    int K, int relu)
{
    __shared__ __align__(16) _Float16 sAh[8*640];
    __shared__ __align__(16) _Float16 sAl[8*640];
    __shared__ __align__(16) _Float16 sBh[8*640];
    __shared__ __align__(16) _Float16 sBl[8*640];

    const int t = threadIdx.x;
    const int z = blockIdx.z;
    const int za = zA + z, zb = zB + z, zc = zC + z;
    const float* Ab = A + (size_t)(za>>1)*sAhi + (size_t)(za&1)*sAlo
                        + (size_t)blockIdx.y*128*lda;
    const float* Bb = B + (size_t)(zb>>1)*sBhi + (size_t)(zb&1)*sBlo
                        + (BN ? (size_t)blockIdx.x*128
                              : (size_t)blockIdx.x*128*ldb);

    const int wv = t >> 6, lane = t & 63;
    const int wm = wv >> 1, wn = wv & 1;
    const int lm = lane & 15, lq = lane >> 4;

    f32x4 acc[4][4];
#pragma unroll
    for (int i = 0; i < 4; ++i)
#pragma unroll
        for (int j = 0; j < 4; ++j) acc[i][j] = (f32x4){0.f,0.f,0.f,0.f};

    const int r8  = t >> 3;         // 0..31 (staging row base)
    const int kc  = (t & 7) * 4;    // 0..28 (staging k chunk)
    const int bnk = (t >> 7) * 16;  // BN staging: k half
    const int bnn = t & 127;        // BN staging: n

    for (int k0 = 0; k0 < K; k0 += 32) {
        float4 ga[4], gb[4]; float gv[16];
#pragma unroll
        for (int i = 0; i < 4; ++i)
            ga[i] = *(const float4*)(Ab + (size_t)(r8 + 32*i)*lda + k0 + kc);
        if (BN) {
#pragma unroll
            for (int i = 0; i < 16; ++i)
                gv[i] = Bb[(size_t)(k0 + bnk + i)*ldb + bnn];
        } else {
#pragma unroll
            for (int i = 0; i < 4; ++i)
                gb[i] = *(const float4*)(Bb + (size_t)(r8 + 32*i)*ldb + k0 + kc);
        }
        __syncthreads();   // previous iteration's fragment reads complete
#pragma unroll
        for (int i = 0; i < 4; ++i) {
            const int row  = r8 + 32*i;
            const int base = (row >> 4)*640 + (row & 15)*40 + kc;
            float4 a = ga[i];
            _Float16 h0 = (_Float16)a.x, h1 = (_Float16)a.y,
                     h2 = (_Float16)a.z, h3 = (_Float16)a.w;
            _Float16 l0 = (_Float16)(a.x - (float)h0),
                     l1 = (_Float16)(a.y - (float)h1),
                     l2 = (_Float16)(a.z - (float)h2),
                     l3 = (_Float16)(a.w - (float)h3);
            *(half4v*)&sAh[base] = (half4v){h0,h1,h2,h3};
            *(half4v*)&sAl[base] = (half4v){l0,l1,l2,l3};
        }
        if (BN) {
#pragma unroll
            for (int i = 0; i < 16; ++i) {
                const int k = bnk + i;
                float v = gv[i];
                _Float16 h = (_Float16)v;
                _Float16 l = (_Float16)(v - (float)h);
                const int base = (bnn >> 4)*640 + (bnn & 15)*40 + k;
                sBh[base] = h;
                sBl[base] = l;
            }
        } else {
#pragma unroll
            for (int i = 0; i < 4; ++i) {
                const int row  = r8 + 32*i;
                const int base = (row >> 4)*640 + (row & 15)*40 + kc;
                float4 b = gb[i];
                _Float16 h0 = (_Float16)b.x, h1 = (_Float16)b.y,
                         h2 = (_Float16)b.z, h3 = (_Float16)b.w;
                _Float16 l0 = (_Float16)(b.x - (float)h0),
                         l1 = (_Float16)(b.y - (float)h1),
                         l2 = (_Float16)(b.z - (float)h2),
                         l3 = (_Float16)(b.w - (float)h3);
                *(half4v*)&sBh[base] = (half4v){h0,h1,h2,h3};
                *(half4v*)&sBl[base] = (half4v){l0,l1,l2,l3};
            }
        }
        __syncthreads();

        half8 bhf[4], blf[4];
#pragma unroll
        for (int j = 0; j < 4; ++j) {
            const int tb = (wn*4 + j)*640 + lm*40 + lq*8;
            bhf[j] = *(const half8*)&sBh[tb];
            blf[j] = *(const half8*)&sBl[tb];
        }
#pragma unroll
        for (int i = 0; i < 4; ++i) {
            const int ta = (wm*4 + i)*640 + lm*40 + lq*8;
            half8 ah = *(const half8*)&sAh[ta];
            half8 al = *(const half8*)&sAl[ta];
#pragma unroll
            for (int j = 0; j < 4; ++j) {
                acc[i][j] = __builtin_amdgcn_mfma_f32_16x16x32_f16(ah, bhf[j], acc[i][j], 0, 0, 0);
                acc[i][j] = __builtin_amdgcn_mfma_f32_16x16x32_f16(al, bhf[j], acc[i][j], 0, 0, 0);
                acc[i][j] = __builtin_amdgcn_mfma_f32_16x16x32_f16(ah, blf[j], acc[i][j], 0, 0, 0);
            }
        }
    }

    // epilogue: C/D layout col = lane&15, row = quad*4 + reg
    float* Cb = C + (size_t)(zc>>1)*sChi + (size_t)(zc&1)*sClo;
#pragma unroll
    for (int j = 0; j < 4; ++j) {
        const int col = blockIdx.x*128 + (wn*4 + j)*16 + lm;
        const float bj = bias ? bias[col] : 0.f;
#pragma unroll
        for (int i = 0; i < 4; ++i) {
            const int row0 = blockIdx.y*128 + (wm*4 + i)*16 + lq*4;
#pragma unroll
            for (int r = 0; r < 4; ++r) {
                float v = acc[i][j][r] + bj;
                if (relu) v = fmaxf(v, 0.f);
                Cb[(size_t)(row0 + r)*ldc + col] = v;
            }
        }
    }
}

// =====================================================================
// Row softmax over scores (in place, fully normalized).
// =====================================================================
__global__ __launch_bounds__(256) void softmax_rows(float* __restrict__ scores)
{
    const int w    = threadIdx.x >> 6;
    const int lane = threadIdx.x & 63;
    const size_t row = (size_t)blockIdx.x * 4 + w;
    float* p = scores + row * SS + lane * 8;
    float4 v0 = *(float4*)(p);
    float4 v1 = *(float4*)(p + 4);
    const float scale = 0.0625f;
    float m = fmaxf(fmaxf(fmaxf(v0.x, v0.y), fmaxf(v0.z, v0.w)),
                    fmaxf(fmaxf(v1.x, v1.y), fmaxf(v1.z, v1.w)));
#pragma unroll
    for (int off = 32; off >= 1; off >>= 1) m = fmaxf(m, __shfl_xor(m, off));
    v0.x = __expf((v0.x - m) * scale); v0.y = __expf((v0.y - m) * scale);
    v0.z = __expf((v0.z - m) * scale); v0.w = __expf((v0.w - m) * scale);
    v1.x = __expf((v1.x - m) * scale); v1.y = __expf((v1.y - m) * scale);
    v1.z = __expf((v1.z - m) * scale); v1.w = __expf((v1.w - m) * scale);
    float sum = v0.x + v0.y + v0.z + v0.w + v1.x + v1.y + v1.z + v1.w;
#pragma unroll
    for (int off = 32; off >= 1; off >>= 1) sum += __shfl_xor(sum, off);
    float inv = 1.f / sum;
    v0.x *= inv; v0.y *= inv; v0.z *= inv; v0.w *= inv;
    v1.x *= inv; v1.y *= inv; v1.z *= inv; v1.w *= inv;
    *(float4*)(p)     = v0;
    *(float4*)(p + 4) = v1;
}

// =====================================================================
// CRF emissions: fc[row][j] = dot(dec[row], crf_w[j]) + crf_b[j]
// =====================================================================
__global__ __launch_bounds__(192) void fc_crf_kernel(
    const float* __restrict__ dec, const float* __restrict__ W,
    const float* __restrict__ bias, float* __restrict__ out)
{
    __shared__ __align__(16) float Ws[NT][516];
    for (int i = threadIdx.x; i < NT*128; i += 192) {
        int j = i >> 7, c = (i & 127) * 4;
        *(float4*)&Ws[j][c] = *(const float4*)(W + (size_t)j*EE + c);
    }
    __syncthreads();
    const int t = threadIdx.x;
    const int rloc = t / NT;
    const int j = t - rloc * NT;
    const int row = blockIdx.x * 8 + rloc;
    const float4* a = (const float4*)(dec + (size_t)row * EE);
    float acc = 0.f;
#pragma unroll 4
    for (int i = 0; i < 128; ++i) {
        float4 x = a[i];
        float4 y = *(const float4*)&Ws[j][i*4];
        acc += x.x*y.x + x.y*y.y + x.z*y.z + x.w*y.w;
    }
    out[(size_t)row * NT + j] = acc + bias[j];
}

// =====================================================================
// CRF + seg, 64-thread blocks, __launch_bounds__(64,1) so the register
// allocator can keep the per-lane arrays in VGPRs (round-6's 256-thread
// merged kernel allocated only 68 VGPRs and spilled the recursion arrays
// to scratch -> 1200 cyc/step).
// blocks 0..95: CRF tasks (forward / viterbi / numerator per batch).
// blocks >= 96: seg head, one row per block.
// Forward uses the factorization exp(sc_i - m + tr_ij) =
// exp(sc_i - m) * etr_ij with etr precomputed: 1 exp/lane/step.
// =====================================================================
__global__ __launch_bounds__(64, 1) void crf_seg_kernel(
    const float* __restrict__ fc, const int* __restrict__ labels,
    const float* __restrict__ start_t, const float* __restrict__ end_t,
    const float* __restrict__ trans, const float* __restrict__ dec,
    const float* __restrict__ ent_w, const float* __restrict__ ent_b,
    float* __restrict__ num, float* __restrict__ den,
    float* __restrict__ crf_out, float* __restrict__ segout)
{
    __shared__ unsigned char hist[(SS-1)*NT];

    const int blk  = blockIdx.x;
    const int lane = threadIdx.x;

    if (blk >= 96) {
        // ---------------- segmentation head: 1 row per block -----------
        const int row = blk - 96;
        const float4* a  = (const float4*)(dec + (size_t)row * EE);
        const float4* w0 = (const float4*)(ent_w);
        const float4* w1 = (const float4*)(ent_w + EE);
        float acc0 = 0.f, acc1 = 0.f;
#pragma unroll
        for (int i = 0; i < 2; ++i) {
            int idx = lane * 2 + i;
            float4 x = a[idx];
            float4 u = w0[idx];
            float4 v = w1[idx];
            acc0 += x.x*u.x + x.y*u.y + x.z*u.z + x.w*u.w;
            acc1 += x.x*v.x + x.y*v.y + x.z*v.z + x.w*v.w;
        }
#pragma unroll
        for (int off = 32; off >= 1; off >>= 1) {
            acc0 += __shfl_xor(acc0, off);
            acc1 += __shfl_xor(acc1, off);
        }
        if (lane == 0) {
            float l0 = acc0 + ent_b[0];
            float l1 = acc1 + ent_b[1];
            float m  = fmaxf(l0, l1);
            float lse = m + __logf(__expf(l0 - m) + __expf(l1 - m));
            segout[(size_t)row*2 + 0] = l0 - lse;
            segout[(size_t)row*2 + 1] = l1 - lse;
        }
        return;
    }

    const int role = blk >> 5;          // 0=forward, 1=viterbi, 2=numerator
    const int b    = blk & 31;
    const float* fcb = fc + (size_t)b * SS * NT;

    if (role == 2) {
        // ---- numerator ----
        float acc = 0.f;
        for (int s = 1 + lane; s < SS; s += 64) {
            int prev = labels[b*SS + s - 1];
            int cur  = labels[b*SS + s];
            acc += trans[prev*NT + cur] + fcb[(size_t)s*NT + cur];
        }
        if (lane == 0) {
            int l0 = labels[b*SS];
            acc += start_t[l0] + fcb[l0] + end_t[labels[b*SS + SS - 1]];
        }
#pragma unroll
        for (int off = 32; off >= 1; off >>= 1) acc += __shfl_xor(acc, off);
        if (lane == 0) num[b] = acc;
        return;
    }

    // lane j owns destination tag j
    const int j = (lane < NT) ? lane : 0;
    float sc = start_t[j] + fcb[j];

    if (role == 0) {
        // ---- forward (log-normalizer) ----
        float etr[NT];
#pragma unroll
        for (int i = 0; i < NT; ++i) etr[i] = __expf(trans[i*NT + j]);
        float em_next = fcb[NT + j];
        for (int s = 1; s < SS; ++s) {
            float em = em_next;
            int snx = (s + 1 < SS) ? s + 1 : s;
            em_next = fcb[(size_t)snx * NT + j];     // prefetch next step
            float sv[NT];
#pragma unroll
            for (int i = 0; i < NT; ++i) sv[i] = __shfl(sc, i);
            // in-place max tree over sv -> m (shared across lanes)
#pragma unroll
            for (int st = 1; st < NT; st <<= 1)
#pragma unroll
                for (int i = 0; i + st < NT; i += 2*st)
                    sv[i] = fmaxf(sv[i], sv[i+st]);
            const float m = sv[0];
            const float eo = __expf(sc - m);          // own exp, 1 per lane
            float ev[NT];
#pragma unroll
            for (int i = 0; i < NT; ++i) ev[i] = __shfl(eo, i);
            float a0 = 0.f, a1 = 0.f, a2 = 0.f, a3 = 0.f;
#pragma unroll
            for (int i = 0; i < NT; i += 4) {
                a0 = fmaf(ev[i+0], etr[i+0], a0);
                a1 = fmaf(ev[i+1], etr[i+1], a1);
                a2 = fmaf(ev[i+2], etr[i+2], a2);
                a3 = fmaf(ev[i+3], etr[i+3], a3);
            }
            sc = m + __logf((a0 + a1) + (a2 + a3)) + em;
        }
        float v = (lane < NT) ? sc + end_t[j] : -1e30f;
        float m2 = v;
#pragma unroll
        for (int off = 32; off >= 1; off >>= 1) m2 = fmaxf(m2, __shfl_xor(m2, off));
        float e = (lane < NT) ? __expf(v - m2) : 0.f;
#pragma unroll
        for (int off = 32; off >= 1; off >>= 1) e += __shfl_xor(e, off);
        if (lane == 0) den[b] = m2 + __logf(e);
    } else {
        // ---- viterbi ----
        float trC[NT];
#pragma unroll
        for (int i = 0; i < NT; ++i) trC[i] = trans[i*NT + j];
        float em_next = fcb[NT + j];
        for (int s = 1; s < SS; ++s) {
            float em = em_next;
            int snx = (s + 1 < SS) ? s + 1 : s;
            em_next = fcb[(size_t)snx * NT + j];
            float tv[NT]; int ti[NT];
#pragma unroll
            for (int i = 0; i < NT; ++i) { tv[i] = __shfl(sc, i) + trC[i]; ti[i] = i; }
            // first-tie argmax tree: lower index wins on equality
#pragma unroll
            for (int st = 1; st < NT; st <<= 1)
#pragma unroll
                for (int i = 0; i + st < NT; i += 2*st)
                    if (tv[i+st] > tv[i]) { tv[i] = tv[i+st]; ti[i] = ti[i+st]; }
            sc = tv[0] + em;
            if (lane < NT) hist[(s-1)*NT + lane] = (unsigned char)ti[0];
        }
        // final argmax over lanes (first-tie, lowest lane wins)
        float bv = (lane < NT) ? sc + end_t[j] : -1e30f;
        int bi = (lane < NT) ? lane : NT;
#pragma unroll
        for (int off = 32; off >= 1; off >>= 1) {
            float ov = __shfl_xor(bv, off);
            int   oi = __shfl_xor(bi, off);
            if (ov > bv || (ov == bv && oi < bi)) { bv = ov; bi = oi; }
        }
        __syncthreads();   // drain LDS history writes before backtrack
        if (lane == 0) {
            int tag = bi;
            crf_out[(size_t)b*SS + SS - 1] = (float)tag;
            for (int s = SS - 2; s >= 0; --s) {
                tag = hist[s*NT + tag];
                crf_out[(size_t)b*SS + s] = (float)tag;
            }
        }
    }
}

// =====================================================================
// Final scalar: -llh = -( sum_b(num[b]-den[b]) / 16384 )
// =====================================================================
__global__ __launch_bounds__(64) void llh_kernel(
    const float* __restrict__ num, const float* __restrict__ den,
    float* __restrict__ out)
{
    int t = threadIdx.x;
    float v = (t < BB) ? (num[t] - den[t]) : 0.f;
#pragma unroll
    for (int off = 32; off >= 1; off >>= 1) v += __shfl_xor(v, off);
    if (t == 0) out[(size_t)MR * 3] = -(v / (float)MR);
}

extern "C" void kernel_launch(void* const* d_in, const int* in_sizes, int n_in,
                              void* d_out, int out_size, void* d_ws, size_t ws_size,
                              hipStream_t stream) {
    const float* enc     = (const float*)d_in[0];
    const int*   labels  = (const int*)  d_in[1];
    // d_in[2] = mask (all ones by construction; unused)
    const float* Win     = (const float*)d_in[3];
    const float* bin     = (const float*)d_in[4];
    const float* Wout    = (const float*)d_in[5];
    const float* bout    = (const float*)d_in[6];
    const float* crf_w   = (const float*)d_in[7];
    const float* crf_b   = (const float*)d_in[8];
    const float* start_t = (const float*)d_in[9];
    const float* end_t   = (const float*)d_in[10];
    const float* trans   = (const float*)d_in[11];
    const float* ent_w   = (const float*)d_in[12];
    const float* ent_b   = (const float*)d_in[13];
    float* out = (float*)d_out;

    // Workspace layout — scores half (33.5 MB) aliases dec; scores are
    // dead before dec is written.
    float* ws   = (float*)d_ws;
    float* qkv  = ws;                                 // 16384*1536
    float* attn = qkv  + (size_t)MR * E3;             // 16384*512
    float* big  = attn + (size_t)MR * EE;             // 8,388,608 floats
    float* sch  = big;                                // scores half: 32*512*512
    float* dec  = big;                                // dec aliases scores
    float* fc   = big  + (size_t)MR * EE;             // 16384*24
    float* num  = fc   + (size_t)MR * NT;             // 32
    float* den  = num  + BB;                          // 32

    dim3 blk(256);
    // 1. qkv = enc @ Win^T + bin
    mfma_gemm<0><<<dim3(E3/128, MR/128, 1), blk, 0, stream>>>(
        enc, EE, 0, 0, 0,  Win, EE, 0, 0, 0,  bin,
        qkv, E3, 0, 0, 0,  EE, 0);
    // 2. attention in two z-passes of 32 (b,h) pairs each
    for (int p = 0; p < 2; ++p) {
        int zoff = p * 32;
        // scores[z][m][n] = Q[m].K[n]
        mfma_gemm<0><<<dim3(SS/128, SS/128, 32), blk, 0, stream>>>(
            qkv,      E3, (long)SS*E3, HDD, zoff,
            qkv + EE, E3, (long)SS*E3, HDD, zoff,
            nullptr,
            sch, SS, 2L*SS*SS, (long)SS*SS, 0,
            HDD, 0);
        softmax_rows<<<(32*SS)/4, blk, 0, stream>>>(sch);
        // attn[b,m,h*256+n] = sum_k P[z][m][k] V[b,k,h][n]
        mfma_gemm<1><<<dim3(HDD/128, SS/128, 32), blk, 0, stream>>>(
            sch, SS, 2L*SS*SS, (long)SS*SS, 0,
            qkv + 2*EE, E3, (long)SS*E3, HDD, zoff,
            nullptr,
            attn, EE, (long)SS*EE, HDD, zoff,
            SS, 0);
    }
    // 3. dec = relu(attn @ Wout^T + bout)   (overwrites scores region)
    mfma_gemm<0><<<dim3(EE/128, MR/128, 1), blk, 0, stream>>>(
        attn, EE, 0, 0, 0,  Wout, EE, 0, 0, 0,  bout,
        dec, EE, 0, 0, 0,  EE, 1);
    // 4. fc emissions
    fc_crf_kernel<<<MR/8, dim3(192), 0, stream>>>(dec, crf_w, crf_b, fc);
    // 5. CRF (forward+viterbi+numerator) + seg head, 64-thread blocks
    crf_seg_kernel<<<96 + MR, dim3(64), 0, stream>>>(
        fc, labels, start_t, end_t, trans, dec, ent_w, ent_b,
        num, den, out, out + MR);
    // 6. -llh scalar -> d_out[49152]
    llh_kernel<<<1, 64, 0, stream>>>(num, den, out);
}

// Round 9
// 572.271 us; speedup vs baseline: 2.8551x; 1.0596x over previous
//
#include <hip/hip_runtime.h>

#define BB 32
#define SS 512
#define EE 512
#define NHH 2
#define HDD 256
#define E3 1536
#define NT 24
#define MR (BB*SS)   // 16384

typedef _Float16 half8  __attribute__((ext_vector_type(8)));
typedef _Float16 half4v __attribute__((ext_vector_type(4)));
typedef float    f32x4  __attribute__((ext_vector_type(4)));

// scalar (SGPR) lane broadcast — index MUST be wave-uniform (constant).
// Round-8 bug: divergent index here is UB (readlane takes firstlane of idx).
__device__ __forceinline__ float rl(float v, int l) {
    return __int_as_float(__builtin_amdgcn_readlane(__float_as_int(v), l));
}

// =====================================================================
// fp32-accurate GEMM via fp16 3-product MFMA split (Ootomo).
// 128x128 block tile, 256 thr = 2x2 waves, 4x4 tiles of 16x16x32 f16.
// BN=0: B is row-major N x K (B^T form). BN=1: B is row-major K x N (V).
// =====================================================================
template<int BN>
__global__ __launch_bounds__(256) void mfma_gemm(
    const float* __restrict__ A, int lda, long sAhi, long sAlo, int zA,
    const float* __restrict__ B, int ldb, long sBhi, long sBlo, int zB,
    const float* __restrict__ bias,
    float* __restrict__ C, int ldc, long sChi, long sClo, int zC,
    int K, int relu)
{
    __shared__ __align__(16) _Float16 sAh[8*640];
    __shared__ __align__(16) _Float16 sAl[8*640];
    __shared__ __align__(16) _Float16 sBh[8*640];
    __shared__ __align__(16) _Float16 sBl[8*640];

    const int t = threadIdx.x;
    const int z = blockIdx.z;
    const int za = zA + z, zb = zB + z, zc = zC + z;
    const float* Ab = A + (size_t)(za>>1)*sAhi + (size_t)(za&1)*sAlo
                        + (size_t)blockIdx.y*128*lda;
    const float* Bb = B + (size_t)(zb>>1)*sBhi + (size_t)(zb&1)*sBlo
                        + (BN ? (size_t)blockIdx.x*128
                              : (size_t)blockIdx.x*128*ldb);

    const int wv = t >> 6, lane = t & 63;
    const int wm = wv >> 1, wn = wv & 1;
    const int lm = lane & 15, lq = lane >> 4;

    f32x4 acc[4][4];
#pragma unroll
    for (int i = 0; i < 4; ++i)
#pragma unroll
        for (int j = 0; j < 4; ++j) acc[i][j] = (f32x4){0.f,0.f,0.f,0.f};

    const int r8  = t >> 3;         // 0..31 (staging row base)
    const int kc  = (t & 7) * 4;    // 0..28 (staging k chunk)
    const int bnk = (t >> 7) * 16;  // BN staging: k half
    const int bnn = t & 127;        // BN staging: n

    for (int k0 = 0; k0 < K; k0 += 32) {
        float4 ga[4], gb[4]; float gv[16];
#pragma unroll
        for (int i = 0; i < 4; ++i)
            ga[i] = *(const float4*)(Ab + (size_t)(r8 + 32*i)*lda + k0 + kc);
        if (BN) {
#pragma unroll
            for (int i = 0; i < 16; ++i)
                gv[i] = Bb[(size_t)(k0 + bnk + i)*ldb + bnn];
        } else {
#pragma unroll
            for (int i = 0; i < 4; ++i)
                gb[i] = *(const float4*)(Bb + (size_t)(r8 + 32*i)*ldb + k0 + kc);
        }
        __syncthreads();   // previous iteration's fragment reads complete
#pragma unroll
        for (int i = 0; i < 4; ++i) {
            const int row  = r8 + 32*i;
            const int base = (row >> 4)*640 + (row & 15)*40 + kc;
            float4 a = ga[i];
            _Float16 h0 = (_Float16)a.x, h1 = (_Float16)a.y,
                     h2 = (_Float16)a.z, h3 = (_Float16)a.w;
            _Float16 l0 = (_Float16)(a.x - (float)h0),
                     l1 = (_Float16)(a.y - (float)h1),
                     l2 = (_Float16)(a.z - (float)h2),
                     l3 = (_Float16)(a.w - (float)h3);
            *(half4v*)&sAh[base] = (half4v){h0,h1,h2,h3};
            *(half4v*)&sAl[base] = (half4v){l0,l1,l2,l3};
        }
        if (BN) {
#pragma unroll
            for (int i = 0; i < 16; ++i) {
                const int k = bnk + i;
                float v = gv[i];
                _Float16 h = (_Float16)v;
                _Float16 l = (_Float16)(v - (float)h);
                const int base = (bnn >> 4)*640 + (bnn & 15)*40 + k;
                sBh[base] = h;
                sBl[base] = l;
            }
        } else {
#pragma unroll
            for (int i = 0; i < 4; ++i) {
                const int row  = r8 + 32*i;
                const int base = (row >> 4)*640 + (row & 15)*40 + kc;
                float4 b = gb[i];
                _Float16 h0 = (_Float16)b.x, h1 = (_Float16)b.y,
                         h2 = (_Float16)b.z, h3 = (_Float16)b.w;
                _Float16 l0 = (_Float16)(b.x - (float)h0),
                         l1 = (_Float16)(b.y - (float)h1),
                         l2 = (_Float16)(b.z - (float)h2),
                         l3 = (_Float16)(b.w - (float)h3);
                *(half4v*)&sBh[base] = (half4v){h0,h1,h2,h3};
                *(half4v*)&sBl[base] = (half4v){l0,l1,l2,l3};
            }
        }
        __syncthreads();

        half8 bhf[4], blf[4];
#pragma unroll
        for (int j = 0; j < 4; ++j) {
            const int tb = (wn*4 + j)*640 + lm*40 + lq*8;
            bhf[j] = *(const half8*)&sBh[tb];
            blf[j] = *(const half8*)&sBl[tb];
        }
#pragma unroll
        for (int i = 0; i < 4; ++i) {
            const int ta = (wm*4 + i)*640 + lm*40 + lq*8;
            half8 ah = *(const half8*)&sAh[ta];
            half8 al = *(const half8*)&sAl[ta];
#pragma unroll
            for (int j = 0; j < 4; ++j) {
                acc[i][j] = __builtin_amdgcn_mfma_f32_16x16x32_f16(ah, bhf[j], acc[i][j], 0, 0, 0);
                acc[i][j] = __builtin_amdgcn_mfma_f32_16x16x32_f16(al, bhf[j], acc[i][j], 0, 0, 0);
                acc[i][j] = __builtin_amdgcn_mfma_f32_16x16x32_f16(ah, blf[j], acc[i][j], 0, 0, 0);
            }
        }
    }

    // epilogue: C/D layout col = lane&15, row = quad*4 + reg
    float* Cb = C + (size_t)(zc>>1)*sChi + (size_t)(zc&1)*sClo;
#pragma unroll
    for (int j = 0; j < 4; ++j) {
        const int col = blockIdx.x*128 + (wn*4 + j)*16 + lm;
        const float bj = bias ? bias[col] : 0.f;
#pragma unroll
        for (int i = 0; i < 4; ++i) {
            const int row0 = blockIdx.y*128 + (wm*4 + i)*16 + lq*4;
#pragma unroll
            for (int r = 0; r < 4; ++r) {
                float v = acc[i][j][r] + bj;
                if (relu) v = fmaxf(v, 0.f);
                Cb[(size_t)(row0 + r)*ldc + col] = v;
            }
        }
    }
}

// =====================================================================
// Row softmax over scores (in place, fully normalized).
// =====================================================================
__global__ __launch_bounds__(256) void softmax_rows(float* __restrict__ scores)
{
    const int w    = threadIdx.x >> 6;
    const int lane = threadIdx.x & 63;
    const size_t row = (size_t)blockIdx.x * 4 + w;
    float* p = scores + row * SS + lane * 8;
    float4 v0 = *(float4*)(p);
    float4 v1 = *(float4*)(p + 4);
    const float scale = 0.0625f;
    float m = fmaxf(fmaxf(fmaxf(v0.x, v0.y), fmaxf(v0.z, v0.w)),
                    fmaxf(fmaxf(v1.x, v1.y), fmaxf(v1.z, v1.w)));
#pragma unroll
    for (int off = 32; off >= 1; off >>= 1) m = fmaxf(m, __shfl_xor(m, off));
    v0.x = __expf((v0.x - m) * scale); v0.y = __expf((v0.y - m) * scale);
    v0.z = __expf((v0.z - m) * scale); v0.w = __expf((v0.w - m) * scale);
    v1.x = __expf((v1.x - m) * scale); v1.y = __expf((v1.y - m) * scale);
    v1.z = __expf((v1.z - m) * scale); v1.w = __expf((v1.w - m) * scale);
    float sum = v0.x + v0.y + v0.z + v0.w + v1.x + v1.y + v1.z + v1.w;
#pragma unroll
    for (int off = 32; off >= 1; off >>= 1) sum += __shfl_xor(sum, off);
    float inv = 1.f / sum;
    v0.x *= inv; v0.y *= inv; v0.z *= inv; v0.w *= inv;
    v1.x *= inv; v1.y *= inv; v1.z *= inv; v1.w *= inv;
    *(float4*)(p)     = v0;
    *(float4*)(p + 4) = v1;
}

// =====================================================================
// CRF emissions: fc[row][j] = dot(dec[row], crf_w[j]) + crf_b[j]
// =====================================================================
__global__ __launch_bounds__(192) void fc_crf_kernel(
    const float* __restrict__ dec, const float* __restrict__ W,
    const float* __restrict__ bias, float* __restrict__ out)
{
    __shared__ __align__(16) float Ws[NT][516];
    for (int i = threadIdx.x; i < NT*128; i += 192) {
        int j = i >> 7, c = (i & 127) * 4;
        *(float4*)&Ws[j][c] = *(const float4*)(W + (size_t)j*EE + c);
    }
    __syncthreads();
    const int t = threadIdx.x;
    const int rloc = t / NT;
    const int j = t - rloc * NT;
    const int row = blockIdx.x * 8 + rloc;
    const float4* a = (const float4*)(dec + (size_t)row * EE);
    float acc = 0.f;
#pragma unroll 4
    for (int i = 0; i < 128; ++i) {
        float4 x = a[i];
        float4 y = *(const float4*)&Ws[j][i*4];
        acc += x.x*y.x + x.y*y.y + x.z*y.z + x.w*y.w;
    }
    out[(size_t)row * NT + j] = acc + bias[j];
}

// =====================================================================
// CRF + seg, 64-thread blocks.
// blocks 0..95: CRF tasks (forward / viterbi / numerator per batch).
// blocks >= 96: seg head, one row per block.
//  - cross-lane broadcasts via v_readlane with CONSTANT indices only
//  - forward: stabilizer m = readfirstlane(sc); 1 exp/lane/step via
//    exp(sc_i - m + tr_ij) = exp(sc_i - m) * etr_ij factorization
//  - viterbi: full 24-candidate first-tie argmax tree per lane
//    (round-8's half-split used a divergent readlane index — UB; reverted)
// =====================================================================
__global__ __launch_bounds__(64, 1) void crf_seg_kernel(
    const float* __restrict__ fc, const int* __restrict__ labels,
    const float* __restrict__ start_t, const float* __restrict__ end_t,
    const float* __restrict__ trans, const float* __restrict__ dec,
    const float* __restrict__ ent_w, const float* __restrict__ ent_b,
    float* __restrict__ num, float* __restrict__ den,
    float* __restrict__ crf_out, float* __restrict__ segout)
{
    __shared__ unsigned char hist[(SS-1)*NT];

    const int blk  = blockIdx.x;
    const int lane = threadIdx.x;

    if (blk >= 96) {
        // ---------------- segmentation head: 1 row per block -----------
        const int row = blk - 96;
        const float4* a  = (const float4*)(dec + (size_t)row * EE);
        const float4* w0 = (const float4*)(ent_w);
        const float4* w1 = (const float4*)(ent_w + EE);
        float acc0 = 0.f, acc1 = 0.f;
#pragma unroll
        for (int i = 0; i < 2; ++i) {
            int idx = lane * 2 + i;
            float4 x = a[idx];
            float4 u = w0[idx];
            float4 v = w1[idx];
            acc0 += x.x*u.x + x.y*u.y + x.z*u.z + x.w*u.w;
            acc1 += x.x*v.x + x.y*v.y + x.z*v.z + x.w*v.w;
        }
#pragma unroll
        for (int off = 32; off >= 1; off >>= 1) {
            acc0 += __shfl_xor(acc0, off);
            acc1 += __shfl_xor(acc1, off);
        }
        if (lane == 0) {
            float l0 = acc0 + ent_b[0];
            float l1 = acc1 + ent_b[1];
            float m  = fmaxf(l0, l1);
            float lse = m + __logf(__expf(l0 - m) + __expf(l1 - m));
            segout[(size_t)row*2 + 0] = l0 - lse;
            segout[(size_t)row*2 + 1] = l1 - lse;
        }
        return;
    }

    const int role = blk >> 5;          // 0=forward, 1=viterbi, 2=numerator
    const int b    = blk & 31;
    const float* fcb = fc + (size_t)b * SS * NT;

    if (role == 2) {
        // ---- numerator ----
        float acc = 0.f;
        for (int s = 1 + lane; s < SS; s += 64) {
            int prev = labels[b*SS + s - 1];
            int cur  = labels[b*SS + s];
            acc += trans[prev*NT + cur] + fcb[(size_t)s*NT + cur];
        }
        if (lane == 0) {
            int l0 = labels[b*SS];
            acc += start_t[l0] + fcb[l0] + end_t[labels[b*SS + SS - 1]];
        }
#pragma unroll
        for (int off = 32; off >= 1; off >>= 1) acc += __shfl_xor(acc, off);
        if (lane == 0) num[b] = acc;
        return;
    }

    // lane j<24 owns destination tag j
    const int j = (lane < NT) ? lane : 0;
    float sc = start_t[j] + fcb[j];

    if (role == 0) {
        // ---- forward (log-normalizer) ----
        float etr[NT];
#pragma unroll
        for (int i = 0; i < NT; ++i) etr[i] = __expf(trans[i*NT + j]);
        float em_next = fcb[NT + j];
        for (int s = 1; s < SS; ++s) {
            float em = em_next;
            int snx = (s + 1 < SS) ? s + 1 : s;
            em_next = fcb[(size_t)snx * NT + j];     // prefetch next step
            const float m  = __builtin_amdgcn_readfirstlane(sc);
            const float eo = __expf(sc - m);          // 1 exp per lane
            float a0 = 0.f, a1 = 0.f, a2 = 0.f, a3 = 0.f;
#pragma unroll
            for (int i = 0; i < NT; i += 4) {
                a0 = fmaf(rl(eo, i+0), etr[i+0], a0);
                a1 = fmaf(rl(eo, i+1), etr[i+1], a1);
                a2 = fmaf(rl(eo, i+2), etr[i+2], a2);
                a3 = fmaf(rl(eo, i+3), etr[i+3], a3);
            }
            sc = m + __logf((a0 + a1) + (a2 + a3)) + em;
        }
        float v = (lane < NT) ? sc + end_t[j] : -1e30f;
        float m2 = v;
#pragma unroll
        for (int off = 32; off >= 1; off >>= 1) m2 = fmaxf(m2, __shfl_xor(m2, off));
        float e = (lane < NT) ? __expf(v - m2) : 0.f;
#pragma unroll
        for (int off = 32; off >= 1; off >>= 1) e += __shfl_xor(e, off);
        if (lane == 0) den[b] = m2 + __logf(e);
    } else {
        // ---- viterbi: full 24-candidate tree, constant-index readlane ----
        float trC[NT];
#pragma unroll
        for (int i = 0; i < NT; ++i) trC[i] = trans[i*NT + j];
        float em_next = fcb[NT + j];
        for (int s = 1; s < SS; ++s) {
            float em = em_next;
            int snx = (s + 1 < SS) ? s + 1 : s;
            em_next = fcb[(size_t)snx * NT + j];
            float tv[NT]; int ti[NT];
#pragma unroll
            for (int i = 0; i < NT; ++i) { tv[i] = rl(sc, i) + trC[i]; ti[i] = i; }
            // first-tie argmax tree: lower index wins on equality
#pragma unroll
            for (int st = 1; st < NT; st <<= 1)
#pragma unroll
                for (int i = 0; i + st < NT; i += 2*st)
                    if (tv[i+st] > tv[i]) { tv[i] = tv[i+st]; ti[i] = ti[i+st]; }
            sc = tv[0] + em;
            if (lane < NT) hist[(s-1)*NT + lane] = (unsigned char)ti[0];
        }
        // final argmax over lanes (first-tie, lowest lane wins)
        float bv = (lane < NT) ? sc + end_t[j] : -1e30f;
        int bi = (lane < NT) ? lane : NT;
#pragma unroll
        for (int off = 32; off >= 1; off >>= 1) {
            float ov = __shfl_xor(bv, off);
            int   oi = __shfl_xor(bi, off);
            if (ov > bv || (ov == bv && oi < bi)) { bv = ov; bi = oi; }
        }
        __syncthreads();   // drain LDS history writes before backtrack
        if (lane == 0) {
            int tag = bi;
            crf_out[(size_t)b*SS + SS - 1] = (float)tag;
            for (int s = SS - 2; s >= 0; --s) {
                tag = hist[s*NT + tag];
                crf_out[(size_t)b*SS + s] = (float)tag;
            }
        }
    }
}

// =====================================================================
// Final scalar: -llh = -( sum_b(num[b]-den[b]) / 16384 )
// =====================================================================
__global__ __launch_bounds__(64) void llh_kernel(
    const float* __restrict__ num, const float* __restrict__ den,
    float* __restrict__ out)
{
    int t = threadIdx.x;
    float v = (t < BB) ? (num[t] - den[t]) : 0.f;
#pragma unroll
    for (int off = 32; off >= 1; off >>= 1) v += __shfl_xor(v, off);
    if (t == 0) out[(size_t)MR * 3] = -(v / (float)MR);
}

extern "C" void kernel_launch(void* const* d_in, const int* in_sizes, int n_in,
                              void* d_out, int out_size, void* d_ws, size_t ws_size,
                              hipStream_t stream) {
    const float* enc     = (const float*)d_in[0];
    const int*   labels  = (const int*)  d_in[1];
    // d_in[2] = mask (all ones by construction; unused)
    const float* Win     = (const float*)d_in[3];
    const float* bin     = (const float*)d_in[4];
    const float* Wout    = (const float*)d_in[5];
    const float* bout    = (const float*)d_in[6];
    const float* crf_w   = (const float*)d_in[7];
    const float* crf_b   = (const float*)d_in[8];
    const float* start_t = (const float*)d_in[9];
    const float* end_t   = (const float*)d_in[10];
    const float* trans   = (const float*)d_in[11];
    const float* ent_w   = (const float*)d_in[12];
    const float* ent_b   = (const float*)d_in[13];
    float* out = (float*)d_out;

    // Workspace layout — scores half (33.5 MB) aliases dec; scores are
    // dead before dec is written.
    float* ws   = (float*)d_ws;
    float* qkv  = ws;                                 // 16384*1536
    float* attn = qkv  + (size_t)MR * E3;             // 16384*512
    float* big  = attn + (size_t)MR * EE;             // 8,388,608 floats
    float* sch  = big;                                // scores half: 32*512*512
    float* dec  = big;                                // dec aliases scores
    float* fc   = big  + (size_t)MR * EE;             // 16384*24
    float* num  = fc   + (size_t)MR * NT;             // 32
    float* den  = num  + BB;                          // 32

    dim3 blk(256);
    // 1. qkv = enc @ Win^T + bin
    mfma_gemm<0><<<dim3(E3/128, MR/128, 1), blk, 0, stream>>>(
        enc, EE, 0, 0, 0,  Win, EE, 0, 0, 0,  bin,
        qkv, E3, 0, 0, 0,  EE, 0);
    // 2. attention in two z-passes of 32 (b,h) pairs each
    for (int p = 0; p < 2; ++p) {
        int zoff = p * 32;
        // scores[z][m][n] = Q[m].K[n]
        mfma_gemm<0><<<dim3(SS/128, SS/128, 32), blk, 0, stream>>>(
            qkv,      E3, (long)SS*E3, HDD, zoff,
            qkv + EE, E3, (long)SS*E3, HDD, zoff,
            nullptr,
            sch, SS, 2L*SS*SS, (long)SS*SS, 0,
            HDD, 0);
        softmax_rows<<<(32*SS)/4, blk, 0, stream>>>(sch);
        // attn[b,m,h*256+n] = sum_k P[z][m][k] V[b,k,h][n]
        mfma_gemm<1><<<dim3(HDD/128, SS/128, 32), blk, 0, stream>>>(
            sch, SS, 2L*SS*SS, (long)SS*SS, 0,
            qkv + 2*EE, E3, (long)SS*E3, HDD, zoff,
            nullptr,
            attn, EE, (long)SS*EE, HDD, zoff,
            SS, 0);
    }
    // 3. dec = relu(attn @ Wout^T + bout)   (overwrites scores region)
    mfma_gemm<0><<<dim3(EE/128, MR/128, 1), blk, 0, stream>>>(
        attn, EE, 0, 0, 0,  Wout, EE, 0, 0, 0,  bout,
        dec, EE, 0, 0, 0,  EE, 1);
    // 4. fc emissions
    fc_crf_kernel<<<MR/8, dim3(192), 0, stream>>>(dec, crf_w, crf_b, fc);
    // 5. CRF (forward+viterbi+numerator) + seg head, 64-thread blocks
    crf_seg_kernel<<<96 + MR, dim3(64), 0, stream>>>(
        fc, labels, start_t, end_t, trans, dec, ent_w, ent_b,
        num, den, out, out + MR);
    // 6. -llh scalar -> d_out[49152]
    llh_kernel<<<1, 64, 0, stream>>>(num, den, out);
}

// Round 10
// 563.887 us; speedup vs baseline: 2.8976x; 1.0149x over previous
//
#include <hip/hip_runtime.h>

#define BB 32
#define SS 512
#define EE 512
#define NHH 2
#define HDD 256
#define E3 1536
#define NT 24
#define MR (BB*SS)   // 16384

typedef _Float16 half8  __attribute__((ext_vector_type(8)));
typedef _Float16 half4v __attribute__((ext_vector_type(4)));
typedef float    f32x4  __attribute__((ext_vector_type(4)));

// scalar (SGPR) lane broadcast — index MUST be wave-uniform (constant).
__device__ __forceinline__ float rl(float v, int l) {
    return __int_as_float(__builtin_amdgcn_readlane(__float_as_int(v), l));
}

// =====================================================================
// fp32-accurate GEMM via fp16 3-product MFMA split (Ootomo).
// 128x128 block tile, 256 thr = 2x2 waves, 4x4 tiles of 16x16x32 f16.
// BN=0: B is row-major N x K (B^T form). BN=1: B is row-major K x N (V).
// =====================================================================
template<int BN>
__global__ __launch_bounds__(256) void mfma_gemm(
    const float* __restrict__ A, int lda, long sAhi, long sAlo, int zA,
    const float* __restrict__ B, int ldb, long sBhi, long sBlo, int zB,
    const float* __restrict__ bias,
    float* __restrict__ C, int ldc, long sChi, long sClo, int zC,
    int K, int relu)
{
    __shared__ __align__(16) _Float16 sAh[8*640];
    __shared__ __align__(16) _Float16 sAl[8*640];
    __shared__ __align__(16) _Float16 sBh[8*640];
    __shared__ __align__(16) _Float16 sBl[8*640];

    const int t = threadIdx.x;
    const int z = blockIdx.z;
    const int za = zA + z, zb = zB + z, zc = zC + z;
    const float* Ab = A + (size_t)(za>>1)*sAhi + (size_t)(za&1)*sAlo
                        + (size_t)blockIdx.y*128*lda;
    const float* Bb = B + (size_t)(zb>>1)*sBhi + (size_t)(zb&1)*sBlo
                        + (BN ? (size_t)blockIdx.x*128
                              : (size_t)blockIdx.x*128*ldb);

    const int wv = t >> 6, lane = t & 63;
    const int wm = wv >> 1, wn = wv & 1;
    const int lm = lane & 15, lq = lane >> 4;

    f32x4 acc[4][4];
#pragma unroll
    for (int i = 0; i < 4; ++i)
#pragma unroll
        for (int j = 0; j < 4; ++j) acc[i][j] = (f32x4){0.f,0.f,0.f,0.f};

    const int r8  = t >> 3;         // 0..31 (staging row base)
    const int kc  = (t & 7) * 4;    // 0..28 (staging k chunk)
    const int bnk = (t >> 7) * 16;  // BN staging: k half
    const int bnn = t & 127;        // BN staging: n

    for (int k0 = 0; k0 < K; k0 += 32) {
        float4 ga[4], gb[4]; float gv[16];
#pragma unroll
        for (int i = 0; i < 4; ++i)
            ga[i] = *(const float4*)(Ab + (size_t)(r8 + 32*i)*lda + k0 + kc);
        if (BN) {
#pragma unroll
            for (int i = 0; i < 16; ++i)
                gv[i] = Bb[(size_t)(k0 + bnk + i)*ldb + bnn];
        } else {
#pragma unroll
            for (int i = 0; i < 4; ++i)
                gb[i] = *(const float4*)(Bb + (size_t)(r8 + 32*i)*ldb + k0 + kc);
        }
        __syncthreads();   // previous iteration's fragment reads complete
#pragma unroll
        for (int i = 0; i < 4; ++i) {
            const int row  = r8 + 32*i;
            const int base = (row >> 4)*640 + (row & 15)*40 + kc;
            float4 a = ga[i];
            _Float16 h0 = (_Float16)a.x, h1 = (_Float16)a.y,
                     h2 = (_Float16)a.z, h3 = (_Float16)a.w;
            _Float16 l0 = (_Float16)(a.x - (float)h0),
                     l1 = (_Float16)(a.y - (float)h1),
                     l2 = (_Float16)(a.z - (float)h2),
                     l3 = (_Float16)(a.w - (float)h3);
            *(half4v*)&sAh[base] = (half4v){h0,h1,h2,h3};
            *(half4v*)&sAl[base] = (half4v){l0,l1,l2,l3};
        }
        if (BN) {
#pragma unroll
            for (int i = 0; i < 16; ++i) {
                const int k = bnk + i;
                float v = gv[i];
                _Float16 h = (_Float16)v;
                _Float16 l = (_Float16)(v - (float)h);
                const int base = (bnn >> 4)*640 + (bnn & 15)*40 + k;
                sBh[base] = h;
                sBl[base] = l;
            }
        } else {
#pragma unroll
            for (int i = 0; i < 4; ++i) {
                const int row  = r8 + 32*i;
                const int base = (row >> 4)*640 + (row & 15)*40 + kc;
                float4 b = gb[i];
                _Float16 h0 = (_Float16)b.x, h1 = (_Float16)b.y,
                         h2 = (_Float16)b.z, h3 = (_Float16)b.w;
                _Float16 l0 = (_Float16)(b.x - (float)h0),
                         l1 = (_Float16)(b.y - (float)h1),
                         l2 = (_Float16)(b.z - (float)h2),
                         l3 = (_Float16)(b.w - (float)h3);
                *(half4v*)&sBh[base] = (half4v){h0,h1,h2,h3};
                *(half4v*)&sBl[base] = (half4v){l0,l1,l2,l3};
            }
        }
        __syncthreads();

        half8 bhf[4], blf[4];
#pragma unroll
        for (int j = 0; j < 4; ++j) {
            const int tb = (wn*4 + j)*640 + lm*40 + lq*8;
            bhf[j] = *(const half8*)&sBh[tb];
            blf[j] = *(const half8*)&sBl[tb];
        }
#pragma unroll
        for (int i = 0; i < 4; ++i) {
            const int ta = (wm*4 + i)*640 + lm*40 + lq*8;
            half8 ah = *(const half8*)&sAh[ta];
            half8 al = *(const half8*)&sAl[ta];
#pragma unroll
            for (int j = 0; j < 4; ++j) {
                acc[i][j] = __builtin_amdgcn_mfma_f32_16x16x32_f16(ah, bhf[j], acc[i][j], 0, 0, 0);
                acc[i][j] = __builtin_amdgcn_mfma_f32_16x16x32_f16(al, bhf[j], acc[i][j], 0, 0, 0);
                acc[i][j] = __builtin_amdgcn_mfma_f32_16x16x32_f16(ah, blf[j], acc[i][j], 0, 0, 0);
            }
        }
    }

    // epilogue: C/D layout col = lane&15, row = quad*4 + reg
    float* Cb = C + (size_t)(zc>>1)*sChi + (size_t)(zc&1)*sClo;
#pragma unroll
    for (int j = 0; j < 4; ++j) {
        const int col = blockIdx.x*128 + (wn*4 + j)*16 + lm;
        const float bj = bias ? bias[col] : 0.f;
#pragma unroll
        for (int i = 0; i < 4; ++i) {
            const int row0 = blockIdx.y*128 + (wm*4 + i)*16 + lq*4;
#pragma unroll
            for (int r = 0; r < 4; ++r) {
                float v = acc[i][j][r] + bj;
                if (relu) v = fmaxf(v, 0.f);
                Cb[(size_t)(row0 + r)*ldc + col] = v;
            }
        }
    }
}

// =====================================================================
// Row softmax over scores (in place, fully normalized).
// =====================================================================
__global__ __launch_bounds__(256) void softmax_rows(float* __restrict__ scores)
{
    const int w    = threadIdx.x >> 6;
    const int lane = threadIdx.x & 63;
    const size_t row = (size_t)blockIdx.x * 4 + w;
    float* p = scores + row * SS + lane * 8;
    float4 v0 = *(float4*)(p);
    float4 v1 = *(float4*)(p + 4);
    const float scale = 0.0625f;
    float m = fmaxf(fmaxf(fmaxf(v0.x, v0.y), fmaxf(v0.z, v0.w)),
                    fmaxf(fmaxf(v1.x, v1.y), fmaxf(v1.z, v1.w)));
#pragma unroll
    for (int off = 32; off >= 1; off >>= 1) m = fmaxf(m, __shfl_xor(m, off));
    v0.x = __expf((v0.x - m) * scale); v0.y = __expf((v0.y - m) * scale);
    v0.z = __expf((v0.z - m) * scale); v0.w = __expf((v0.w - m) * scale);
    v1.x = __expf((v1.x - m) * scale); v1.y = __expf((v1.y - m) * scale);
    v1.z = __expf((v1.z - m) * scale); v1.w = __expf((v1.w - m) * scale);
    float sum = v0.x + v0.y + v0.z + v0.w + v1.x + v1.y + v1.z + v1.w;
#pragma unroll
    for (int off = 32; off >= 1; off >>= 1) sum += __shfl_xor(sum, off);
    float inv = 1.f / sum;
    v0.x *= inv; v0.y *= inv; v0.z *= inv; v0.w *= inv;
    v1.x *= inv; v1.y *= inv; v1.z *= inv; v1.w *= inv;
    *(float4*)(p)     = v0;
    *(float4*)(p + 4) = v1;
}

// =====================================================================
// CRF emissions: fc[row][j] = dot(dec[row], crf_w[j]) + crf_b[j]
// =====================================================================
__global__ __launch_bounds__(192) void fc_crf_kernel(
    const float* __restrict__ dec, const float* __restrict__ W,
    const float* __restrict__ bias, float* __restrict__ out)
{
    __shared__ __align__(16) float Ws[NT][516];
    for (int i = threadIdx.x; i < NT*128; i += 192) {
        int j = i >> 7, c = (i & 127) * 4;
        *(float4*)&Ws[j][c] = *(const float4*)(W + (size_t)j*EE + c);
    }
    __syncthreads();
    const int t = threadIdx.x;
    const int rloc = t / NT;
    const int j = t - rloc * NT;
    const int row = blockIdx.x * 8 + rloc;
    const float4* a = (const float4*)(dec + (size_t)row * EE);
    float acc = 0.f;
#pragma unroll 4
    for (int i = 0; i < 128; ++i) {
        float4 x = a[i];
        float4 y = *(const float4*)&Ws[j][i*4];
        acc += x.x*y.x + x.y*y.y + x.z*y.z + x.w*y.w;
    }
    out[(size_t)row * NT + j] = acc + bias[j];
}

// =====================================================================
// CRF + seg, 64-thread blocks.
// blocks 0..95: CRF tasks (forward / viterbi / numerator per batch).
// blocks >= 96: seg head, one row per block.
// Round-10 change: forward/viterbi stage the batch's full emission
// matrix (512x24 = 48 KB) into LDS up-front with a bulk load (dozens of
// outstanding dwordx4), then the serial recursion reads LDS only.
// Round-9 counters showed 763 cyc/step = HBM-latency-bound on the
// 1-step-ahead global emission prefetch (fc written by other XCDs;
// ~900cyc miss), vs ~250 cyc of VALU per step.
// =====================================================================
__global__ __launch_bounds__(64, 1) void crf_seg_kernel(
    const float* __restrict__ fc, const int* __restrict__ labels,
    const float* __restrict__ start_t, const float* __restrict__ end_t,
    const float* __restrict__ trans, const float* __restrict__ dec,
    const float* __restrict__ ent_w, const float* __restrict__ ent_b,
    float* __restrict__ num, float* __restrict__ den,
    float* __restrict__ crf_out, float* __restrict__ segout)
{
    __shared__ __align__(16) float fc_lds[SS*NT];     // 48 KB
    __shared__ unsigned char hist[(SS-1)*NT];         // 12 KB

    const int blk  = blockIdx.x;
    const int lane = threadIdx.x;

    if (blk >= 96) {
        // ---------------- segmentation head: 1 row per block -----------
        const int row = blk - 96;
        const float4* a  = (const float4*)(dec + (size_t)row * EE);
        const float4* w0 = (const float4*)(ent_w);
        const float4* w1 = (const float4*)(ent_w + EE);
        float acc0 = 0.f, acc1 = 0.f;
#pragma unroll
        for (int i = 0; i < 2; ++i) {
            int idx = lane * 2 + i;
            float4 x = a[idx];
            float4 u = w0[idx];
            float4 v = w1[idx];
            acc0 += x.x*u.x + x.y*u.y + x.z*u.z + x.w*u.w;
            acc1 += x.x*v.x + x.y*v.y + x.z*v.z + x.w*v.w;
        }
#pragma unroll
        for (int off = 32; off >= 1; off >>= 1) {
            acc0 += __shfl_xor(acc0, off);
            acc1 += __shfl_xor(acc1, off);
        }
        if (lane == 0) {
            float l0 = acc0 + ent_b[0];
            float l1 = acc1 + ent_b[1];
            float m  = fmaxf(l0, l1);
            float lse = m + __logf(__expf(l0 - m) + __expf(l1 - m));
            segout[(size_t)row*2 + 0] = l0 - lse;
            segout[(size_t)row*2 + 1] = l1 - lse;
        }
        return;
    }

    const int role = blk >> 5;          // 0=forward, 1=viterbi, 2=numerator
    const int b    = blk & 31;
    const float* fcb = fc + (size_t)b * SS * NT;

    if (role == 2) {
        // ---- numerator (one pass, already parallel; no LDS needed) ----
        float acc = 0.f;
        for (int s = 1 + lane; s < SS; s += 64) {
            int prev = labels[b*SS + s - 1];
            int cur  = labels[b*SS + s];
            acc += trans[prev*NT + cur] + fcb[(size_t)s*NT + cur];
        }
        if (lane == 0) {
            int l0 = labels[b*SS];
            acc += start_t[l0] + fcb[l0] + end_t[labels[b*SS + SS - 1]];
        }
#pragma unroll
        for (int off = 32; off >= 1; off >>= 1) acc += __shfl_xor(acc, off);
        if (lane == 0) num[b] = acc;
        return;
    }

    // ---- bulk-stage emissions into LDS: 12288 floats, 48 float4/lane ----
#pragma unroll
    for (int i = 0; i < SS*NT/256; ++i) {
        const int idx = i*256 + lane*4;
        *(float4*)&fc_lds[idx] = *(const float4*)(fcb + idx);
    }
    __syncthreads();

    // lane j<24 owns destination tag j
    const int j = (lane < NT) ? lane : 0;
    float sc = start_t[j] + fc_lds[j];

    if (role == 0) {
        // ---- forward (log-normalizer) ----
        float etr[NT];
#pragma unroll
        for (int i = 0; i < NT; ++i) etr[i] = __expf(trans[i*NT + j]);
        float em_next = fc_lds[NT + j];
        for (int s = 1; s < SS; ++s) {
            float em = em_next;
            int snx = (s + 1 < SS) ? s + 1 : s;
            em_next = fc_lds[snx * NT + j];          // LDS prefetch
            const float m  = __builtin_amdgcn_readfirstlane(sc);
            const float eo = __expf(sc - m);          // 1 exp per lane
            float a0 = 0.f, a1 = 0.f, a2 = 0.f, a3 = 0.f;
#pragma unroll
            for (int i = 0; i < NT; i += 4) {
                a0 = fmaf(rl(eo, i+0), etr[i+0], a0);
                a1 = fmaf(rl(eo, i+1), etr[i+1], a1);
                a2 = fmaf(rl(eo, i+2), etr[i+2], a2);
                a3 = fmaf(rl(eo, i+3), etr[i+3], a3);
            }
            sc = m + __logf((a0 + a1) + (a2 + a3)) + em;
        }
        float v = (lane < NT) ? sc + end_t[j] : -1e30f;
        float m2 = v;
#pragma unroll
        for (int off = 32; off >= 1; off >>= 1) m2 = fmaxf(m2, __shfl_xor(m2, off));
        float e = (lane < NT) ? __expf(v - m2) : 0.f;
#pragma unroll
        for (int off = 32; off >= 1; off >>= 1) e += __shfl_xor(e, off);
        if (lane == 0) den[b] = m2 + __logf(e);
    } else {
        // ---- viterbi: full 24-candidate tree, constant-index readlane ----
        float trC[NT];
#pragma unroll
        for (int i = 0; i < NT; ++i) trC[i] = trans[i*NT + j];
        float em_next = fc_lds[NT + j];
        for (int s = 1; s < SS; ++s) {
            float em = em_next;
            int snx = (s + 1 < SS) ? s + 1 : s;
            em_next = fc_lds[snx * NT + j];
            float tv[NT]; int ti[NT];
#pragma unroll
            for (int i = 0; i < NT; ++i) { tv[i] = rl(sc, i) + trC[i]; ti[i] = i; }
            // first-tie argmax tree: lower index wins on equality
#pragma unroll
            for (int st = 1; st < NT; st <<= 1)
#pragma unroll
                for (int i = 0; i + st < NT; i += 2*st)
                    if (tv[i+st] > tv[i]) { tv[i] = tv[i+st]; ti[i] = ti[i+st]; }
            sc = tv[0] + em;
            if (lane < NT) hist[(s-1)*NT + lane] = (unsigned char)ti[0];
        }
        // final argmax over lanes (first-tie, lowest lane wins)
        float bv = (lane < NT) ? sc + end_t[j] : -1e30f;
        int bi = (lane < NT) ? lane : NT;
#pragma unroll
        for (int off = 32; off >= 1; off >>= 1) {
            float ov = __shfl_xor(bv, off);
            int   oi = __shfl_xor(bi, off);
            if (ov > bv || (ov == bv && oi < bi)) { bv = ov; bi = oi; }
        }
        __syncthreads();   // drain LDS history writes before backtrack
        if (lane == 0) {
            int tag = bi;
            crf_out[(size_t)b*SS + SS - 1] = (float)tag;
            for (int s = SS - 2; s >= 0; --s) {
                tag = hist[s*NT + tag];
                crf_out[(size_t)b*SS + s] = (float)tag;
            }
        }
    }
}

// =====================================================================
// Final scalar: -llh = -( sum_b(num[b]-den[b]) / 16384 )
// =====================================================================
__global__ __launch_bounds__(64) void llh_kernel(
    const float* __restrict__ num, const float* __restrict__ den,
    float* __restrict__ out)
{
    int t = threadIdx.x;
    float v = (t < BB) ? (num[t] - den[t]) : 0.f;
#pragma unroll
    for (int off = 32; off >= 1; off >>= 1) v += __shfl_xor(v, off);
    if (t == 0) out[(size_t)MR * 3] = -(v / (float)MR);
}

extern "C" void kernel_launch(void* const* d_in, const int* in_sizes, int n_in,
                              void* d_out, int out_size, void* d_ws, size_t ws_size,
                              hipStream_t stream) {
    const float* enc     = (const float*)d_in[0];
    const int*   labels  = (const int*)  d_in[1];
    // d_in[2] = mask (all ones by construction; unused)
    const float* Win     = (const float*)d_in[3];
    const float* bin     = (const float*)d_in[4];
    const float* Wout    = (const float*)d_in[5];
    const float* bout    = (const float*)d_in[6];
    const float* crf_w   = (const float*)d_in[7];
    const float* crf_b   = (const float*)d_in[8];
    const float* start_t = (const float*)d_in[9];
    const float* end_t   = (const float*)d_in[10];
    const float* trans   = (const float*)d_in[11];
    const float* ent_w   = (const float*)d_in[12];
    const float* ent_b   = (const float*)d_in[13];
    float* out = (float*)d_out;

    // Workspace layout — scores half (33.5 MB) aliases dec; scores are
    // dead before dec is written.
    float* ws   = (float*)d_ws;
    float* qkv  = ws;                                 // 16384*1536
    float* attn = qkv  + (size_t)MR * E3;             // 16384*512
    float* big  = attn + (size_t)MR * EE;             // 8,388,608 floats
    float* sch  = big;                                // scores half: 32*512*512
    float* dec  = big;                                // dec aliases scores
    float* fc   = big  + (size_t)MR * EE;             // 16384*24
    float* num  = fc   + (size_t)MR * NT;             // 32
    float* den  = num  + BB;                          // 32

    dim3 blk(256);
    // 1. qkv = enc @ Win^T + bin
    mfma_gemm<0><<<dim3(E3/128, MR/128, 1), blk, 0, stream>>>(
        enc, EE, 0, 0, 0,  Win, EE, 0, 0, 0,  bin,
        qkv, E3, 0, 0, 0,  EE, 0);
    // 2. attention in two z-passes of 32 (b,h) pairs each
    for (int p = 0; p < 2; ++p) {
        int zoff = p * 32;
        // scores[z][m][n] = Q[m].K[n]
        mfma_gemm<0><<<dim3(SS/128, SS/128, 32), blk, 0, stream>>>(
            qkv,      E3, (long)SS*E3, HDD, zoff,
            qkv + EE, E3, (long)SS*E3, HDD, zoff,
            nullptr,
            sch, SS, 2L*SS*SS, (long)SS*SS, 0,
            HDD, 0);
        softmax_rows<<<(32*SS)/4, blk, 0, stream>>>(sch);
        // attn[b,m,h*256+n] = sum_k P[z][m][k] V[b,k,h][n]
        mfma_gemm<1><<<dim3(HDD/128, SS/128, 32), blk, 0, stream>>>(
            sch, SS, 2L*SS*SS, (long)SS*SS, 0,
            qkv + 2*EE, E3, (long)SS*E3, HDD, zoff,
            nullptr,
            attn, EE, (long)SS*EE, HDD, zoff,
            SS, 0);
    }
    // 3. dec = relu(attn @ Wout^T + bout)   (overwrites scores region)
    mfma_gemm<0><<<dim3(EE/128, MR/128, 1), blk, 0, stream>>>(
        attn, EE, 0, 0, 0,  Wout, EE, 0, 0, 0,  bout,
        dec, EE, 0, 0, 0,  EE, 1);
    // 4. fc emissions
    fc_crf_kernel<<<MR/8, dim3(192), 0, stream>>>(dec, crf_w, crf_b, fc);
    // 5. CRF (forward+viterbi+numerator) + seg head, 64-thread blocks
    crf_seg_kernel<<<96 + MR, dim3(64), 0, stream>>>(
        fc, labels, start_t, end_t, trans, dec, ent_w, ent_b,
        num, den, out, out + MR);
    // 6. -llh scalar -> d_out[49152]
    llh_kernel<<<1, 64, 0, stream>>>(num, den, out);
}